// Round 5
// baseline (362.949 us; speedup 1.0000x reference)
//
#include <hip/hip_runtime.h>
#include <hip/hip_bf16.h>
#include <hip/hip_fp16.h>

#define IN_DIM 128
#define HID 8
#define RW 128          // node range width
#define MAXR 1024       // max ranges
#define CCH 512         // edge chunks for count/scatter

// ---------------- pass1: per-chunk range histograms (int4-vectorized) ----------------
__global__ __launch_bounds__(256) void pass1_count(const int* __restrict__ src, const int* __restrict__ dst,
        int* __restrict__ cnt_d, int* __restrict__ cnt_s, int E, int R, int chunk) {
    __shared__ int cd[MAXR], cs[MAXR];
    int t = threadIdx.x, c = blockIdx.x;
    for (int i = t; i < R; i += 256) { cd[i] = 0; cs[i] = 0; }
    __syncthreads();
    int lo = c * chunk, hi = min(lo + chunk, E);
    if (lo < hi) {
        const int4* s4 = reinterpret_cast<const int4*>(src);
        const int4* d4 = reinterpret_cast<const int4*>(dst);
        int q0 = lo >> 2, q1 = hi >> 2;
        for (int q = q0 + t; q < q1; q += 256) {
            int4 d = d4[q], s = s4[q];
            atomicAdd(&cd[d.x >> 7], 1); atomicAdd(&cd[d.y >> 7], 1);
            atomicAdd(&cd[d.z >> 7], 1); atomicAdd(&cd[d.w >> 7], 1);
            atomicAdd(&cs[s.x >> 7], 1); atomicAdd(&cs[s.y >> 7], 1);
            atomicAdd(&cs[s.z >> 7], 1); atomicAdd(&cs[s.w >> 7], 1);
        }
        for (int i = (q1 << 2) + t; i < hi; i += 256) {
            atomicAdd(&cd[dst[i] >> 7], 1);
            atomicAdd(&cs[src[i] >> 7], 1);
        }
    }
    __syncthreads();
    for (int i = t; i < R; i += 256) {
        cnt_d[(size_t)c * R + i] = cd[i];
        cnt_s[(size_t)c * R + i] = cs[i];
    }
}

// ---------------- scan1: per-range exclusive scan over chunks + totals ----------------
__global__ __launch_bounds__(256) void scan1_kernel(int* __restrict__ cnt_d, int* __restrict__ cnt_s,
        int* __restrict__ tot_d, int* __restrict__ tot_s, int R) {
    int r = blockIdx.x;
    int* cnt = blockIdx.y ? cnt_s : cnt_d;
    int* tot = blockIdx.y ? tot_s : tot_d;
    __shared__ int sh[256];
    int t = threadIdx.x;
    int e0 = cnt[(size_t)(2 * t) * R + r];
    int e1 = cnt[(size_t)(2 * t + 1) * R + r];
    int s = e0 + e1;
    sh[t] = s;
    __syncthreads();
    for (int off = 1; off < 256; off <<= 1) {
        int v = (t >= off) ? sh[t - off] : 0;
        __syncthreads();
        sh[t] += v;
        __syncthreads();
    }
    int exc = sh[t] - s;
    cnt[(size_t)(2 * t) * R + r] = exc;
    cnt[(size_t)(2 * t + 1) * R + r] = exc + e0;
    if (t == 255) tot[r] = sh[255];
}

// ---------------- scan2: exclusive scan of range totals -> bucket bases ----------------
__global__ __launch_bounds__(256) void scan2_kernel(const int* __restrict__ tot_d, const int* __restrict__ tot_s,
        int* __restrict__ base_d, int* __restrict__ base_s, int R) {
    const int* tot = blockIdx.x ? tot_s : tot_d;
    int* base = blockIdx.x ? base_s : base_d;
    __shared__ int sh[256];
    int t = threadIdx.x;
    int K = (R + 255) / 256;
    int vals[4];
    int s = 0;
    for (int k = 0; k < K; ++k) {
        int i = t * K + k;
        int v = (i < R) ? tot[i] : 0;
        vals[k] = v; s += v;
    }
    sh[t] = s;
    __syncthreads();
    for (int off = 1; off < 256; off <<= 1) {
        int v = (t >= off) ? sh[t - off] : 0;
        __syncthreads();
        sh[t] += v;
        __syncthreads();
    }
    int exc = sh[t] - s;
    for (int k = 0; k < K; ++k) {
        int i = t * K + k;
        if (i < R) base[i] = exc;
        exc += vals[k];
    }
    if (t == 255) base[R] = sh[255];
}

// ---------------- scatter: dst-sorted (src<<7|dl) + src-sorted (pd<<7|sl) ----------------
__global__ __launch_bounds__(256) void scatter_kernel(const int* __restrict__ src, const int* __restrict__ dst,
        const int* __restrict__ cnt_d, const int* __restrict__ cnt_s,
        const int* __restrict__ base_d, const int* __restrict__ base_s,
        unsigned int* __restrict__ bucket_d, unsigned int* __restrict__ bucket_sv,
        int E, int R, int chunk) {
    __shared__ int od[MAXR], os[MAXR];
    int t = threadIdx.x, c = blockIdx.x;
    for (int i = t; i < R; i += 256) {
        od[i] = base_d[i] + cnt_d[(size_t)c * R + i];
        os[i] = base_s[i] + cnt_s[(size_t)c * R + i];
    }
    __syncthreads();
    int lo = c * chunk, hi = min(lo + chunk, E);
    if (lo >= hi) return;
    const int4* s4 = reinterpret_cast<const int4*>(src);
    const int4* d4 = reinterpret_cast<const int4*>(dst);
    int q0 = lo >> 2, q1 = hi >> 2;
    for (int q = q0 + t; q < q1; q += 256) {
        int4 d = d4[q], s = s4[q];
        int pd, ps;
        pd = atomicAdd(&od[d.x >> 7], 1); bucket_d[pd] = ((unsigned)s.x << 7) | (unsigned)(d.x & 127);
        ps = atomicAdd(&os[s.x >> 7], 1); bucket_sv[ps] = ((unsigned)pd << 7) | (unsigned)(s.x & 127);
        pd = atomicAdd(&od[d.y >> 7], 1); bucket_d[pd] = ((unsigned)s.y << 7) | (unsigned)(d.y & 127);
        ps = atomicAdd(&os[s.y >> 7], 1); bucket_sv[ps] = ((unsigned)pd << 7) | (unsigned)(s.y & 127);
        pd = atomicAdd(&od[d.z >> 7], 1); bucket_d[pd] = ((unsigned)s.z << 7) | (unsigned)(d.z & 127);
        ps = atomicAdd(&os[s.z >> 7], 1); bucket_sv[ps] = ((unsigned)pd << 7) | (unsigned)(s.z & 127);
        pd = atomicAdd(&od[d.w >> 7], 1); bucket_d[pd] = ((unsigned)s.w << 7) | (unsigned)(d.w & 127);
        ps = atomicAdd(&os[s.w >> 7], 1); bucket_sv[ps] = ((unsigned)pd << 7) | (unsigned)(s.w & 127);
    }
    for (int i = (q1 << 2) + t; i < hi; i += 256) {
        int s = src[i], d = dst[i];
        int pd = atomicAdd(&od[d >> 7], 1);
        bucket_d[pd] = ((unsigned)s << 7) | (unsigned)(d & 127);
        int ps = atomicAdd(&os[s >> 7], 1);
        bucket_sv[ps] = ((unsigned)pd << 7) | (unsigned)(s & 127);
    }
}

// ---------------- deg_out: per-range count of src locals ----------------
__global__ __launch_bounds__(256) void degout_kernel(const unsigned int* __restrict__ bucket_sv,
        const int* __restrict__ base_s, float* __restrict__ deg_out, int N) {
    __shared__ int cnt[RW];
    int r = blockIdx.x, t = threadIdx.x;
    if (t < RW) cnt[t] = 0;
    __syncthreads();
    int lo = base_s[r], hi = base_s[r + 1];
    for (int i = lo + t; i < hi; i += 256) atomicAdd(&cnt[bucket_sv[i] & 127], 1);
    __syncthreads();
    if (t < RW) {
        int node = r * RW + t;
        if (node < N) deg_out[node] = (float)cnt[t];
    }
}

// ---------------- conv1: h = (x * norm_out) @ W1, packed to f16x8 (16B/node) ----------------
__global__ __launch_bounds__(256) void conv1_kernel(
        const float* __restrict__ x, const float* __restrict__ W1,
        const float* __restrict__ deg_out, uint4* __restrict__ h4, int N) {
    __shared__ float wt[HID * 132];
    int t = threadIdx.x;
    for (int i = t; i < IN_DIM * HID; i += 256) {
        int k = i >> 3, j = i & 7;
        wt[j * 132 + k] = W1[i];
    }
    __syncthreads();
    int grp = t >> 3, lane = t & 7;
    int node = blockIdx.x * 32 + grp;
    if (node >= N) return;
    const float4* xp = reinterpret_cast<const float4*>(x + (size_t)node * IN_DIM);
    float4 xv[4];
    #pragma unroll
    for (int m = 0; m < 4; ++m) xv[m] = xp[lane + m * 8];
    float acc[HID];
    #pragma unroll
    for (int j = 0; j < HID; ++j) acc[j] = 0.f;
    #pragma unroll
    for (int j = 0; j < HID; ++j) {
        #pragma unroll
        for (int m = 0; m < 4; ++m) {
            float4 wv = *reinterpret_cast<const float4*>(&wt[j * 132 + lane * 4 + m * 32]);
            acc[j] += xv[m].x * wv.x + xv[m].y * wv.y + xv[m].z * wv.z + xv[m].w * wv.w;
        }
    }
    #pragma unroll
    for (int off = 1; off < 8; off <<= 1) {
        #pragma unroll
        for (int j = 0; j < HID; ++j) acc[j] += __shfl_xor(acc[j], off, 64);
    }
    if (lane == 0) {
        float nrm = rsqrtf(fmaxf(deg_out[node], 1.0f));
        __half2 p0 = __floats2half2_rn(acc[0] * nrm, acc[1] * nrm);
        __half2 p1 = __floats2half2_rn(acc[2] * nrm, acc[3] * nrm);
        __half2 p2 = __floats2half2_rn(acc[4] * nrm, acc[5] * nrm);
        __half2 p3 = __floats2half2_rn(acc[6] * nrm, acc[7] * nrm);
        uint4 o;
        o.x = *reinterpret_cast<unsigned*>(&p0);
        o.y = *reinterpret_cast<unsigned*>(&p1);
        o.z = *reinterpret_cast<unsigned*>(&p2);
        o.w = *reinterpret_cast<unsigned*>(&p3);
        h4[node] = o;
    }
}

// ---------------- shuffle1: src-range block, LDS h-slice, write msgs to dst-sorted slots ----------------
__global__ __launch_bounds__(256) void shuffle1_kernel(const unsigned int* __restrict__ bucket_sv,
        const int* __restrict__ base_s, const uint4* __restrict__ h4,
        uint4* __restrict__ msgbuf, int N) {
    __shared__ uint4 hs[RW];
    int r = blockIdx.x, t = threadIdx.x;
    if (t < RW) {
        int node = r * RW + t;
        hs[t] = (node < N) ? h4[node] : make_uint4(0u, 0u, 0u, 0u);
    }
    __syncthreads();
    int lo = base_s[r], hi = base_s[r + 1];
    int i = lo + t;
    for (; i + 768 < hi; i += 1024) {
        unsigned e0 = bucket_sv[i], e1 = bucket_sv[i + 256], e2 = bucket_sv[i + 512], e3 = bucket_sv[i + 768];
        uint4 m0 = hs[e0 & 127], m1 = hs[e1 & 127], m2 = hs[e2 & 127], m3 = hs[e3 & 127];
        msgbuf[e0 >> 7] = m0;
        msgbuf[e1 >> 7] = m1;
        msgbuf[e2 >> 7] = m2;
        msgbuf[e3 >> 7] = m3;
    }
    for (; i < hi; i += 256) {
        unsigned e = bucket_sv[i];
        msgbuf[e >> 7] = hs[e & 127];
    }
}

// ---------------- agg1: sequential msg read, LDS aggregate, finalize h2, shuffle layer-2 msgs ----------------
__device__ __forceinline__ void addEdge1(float* tile, int* cnt, unsigned p, uint4 g) {
    int l = p & 127;
    __half2 q0 = *reinterpret_cast<__half2*>(&g.x);
    __half2 q1 = *reinterpret_cast<__half2*>(&g.y);
    __half2 q2 = *reinterpret_cast<__half2*>(&g.z);
    __half2 q3 = *reinterpret_cast<__half2*>(&g.w);
    float2 f0 = __half22float2(q0), f1 = __half22float2(q1);
    float2 f2 = __half22float2(q2), f3 = __half22float2(q3);
    atomicAdd(&cnt[l], 1);
    atomicAdd(&tile[0 * RW + l], f0.x);
    atomicAdd(&tile[1 * RW + l], f0.y);
    atomicAdd(&tile[2 * RW + l], f1.x);
    atomicAdd(&tile[3 * RW + l], f1.y);
    atomicAdd(&tile[4 * RW + l], f2.x);
    atomicAdd(&tile[5 * RW + l], f2.y);
    atomicAdd(&tile[6 * RW + l], f3.x);
    atomicAdd(&tile[7 * RW + l], f3.y);
}

__global__ __launch_bounds__(256) void agg1_kernel(const unsigned int* __restrict__ bucket_d,
        const int* __restrict__ base_d, const uint4* __restrict__ msgbuf,
        const unsigned int* __restrict__ bucket_sv, const int* __restrict__ base_s,
        const float* __restrict__ deg_out, const float* __restrict__ b1, const float* __restrict__ W2,
        float* __restrict__ deg_in, float* __restrict__ msg2buf, int N) {
    __shared__ float tile[HID * RW];
    __shared__ int cnt[RW];
    __shared__ float h2loc[RW];
    int r = blockIdx.x, t = threadIdx.x;
    for (int i = t; i < HID * RW; i += 256) tile[i] = 0.f;
    if (t < RW) cnt[t] = 0;
    __syncthreads();
    int lo = base_d[r], hi = base_d[r + 1];
    int i = lo + t;
    for (; i + 768 < hi; i += 1024) {
        unsigned p0 = bucket_d[i], p1 = bucket_d[i + 256], p2 = bucket_d[i + 512], p3 = bucket_d[i + 768];
        uint4 g0 = msgbuf[i], g1 = msgbuf[i + 256], g2 = msgbuf[i + 512], g3 = msgbuf[i + 768];
        addEdge1(tile, cnt, p0, g0);
        addEdge1(tile, cnt, p1, g1);
        addEdge1(tile, cnt, p2, g2);
        addEdge1(tile, cnt, p3, g3);
    }
    for (; i < hi; i += 256) {
        unsigned p = bucket_d[i];
        uint4 g = msgbuf[i];
        addEdge1(tile, cnt, p, g);
    }
    __syncthreads();
    if (t < RW) {
        int node = r * RW + t;
        float v = 0.f;
        if (node < N) {
            float din = (float)cnt[t];
            deg_in[node] = din;
            float nin = rsqrtf(fmaxf(din, 1.f));
            float nout = rsqrtf(fmaxf(deg_out[node], 1.f));
            float dot = 0.f;
            #pragma unroll
            for (int j = 0; j < HID; ++j) {
                float y = fmaxf(tile[j * RW + t] * nin + b1[j], 0.f);
                dot += y * W2[j];
            }
            v = dot * nout;
        }
        h2loc[t] = v;
    }
    __syncthreads();
    // layer-2 shuffle: this block's node window IS src-range r
    int slo = base_s[r], shi = base_s[r + 1];
    int k = slo + t;
    for (; k + 768 < shi; k += 1024) {
        unsigned e0 = bucket_sv[k], e1 = bucket_sv[k + 256], e2 = bucket_sv[k + 512], e3 = bucket_sv[k + 768];
        float v0 = h2loc[e0 & 127], v1 = h2loc[e1 & 127], v2 = h2loc[e2 & 127], v3 = h2loc[e3 & 127];
        msg2buf[e0 >> 7] = v0;
        msg2buf[e1 >> 7] = v1;
        msg2buf[e2 >> 7] = v2;
        msg2buf[e3 >> 7] = v3;
    }
    for (; k < shi; k += 256) {
        unsigned e = bucket_sv[k];
        msg2buf[e >> 7] = h2loc[e & 127];
    }
}

// ---------------- agg2: sequential msg2 read, LDS aggregate, final output ----------------
__global__ __launch_bounds__(256) void agg2_kernel(const unsigned int* __restrict__ bucket_d,
        const int* __restrict__ base_d, const float* __restrict__ msg2buf,
        const float* __restrict__ deg_in, const float* __restrict__ b2,
        float* __restrict__ out, int N) {
    __shared__ float tile[RW];
    int r = blockIdx.x, t = threadIdx.x;
    if (t < RW) tile[t] = 0.f;
    __syncthreads();
    int lo = base_d[r], hi = base_d[r + 1];
    int i = lo + t;
    for (; i + 768 < hi; i += 1024) {
        unsigned p0 = bucket_d[i], p1 = bucket_d[i + 256], p2 = bucket_d[i + 512], p3 = bucket_d[i + 768];
        float v0 = msg2buf[i], v1 = msg2buf[i + 256], v2 = msg2buf[i + 512], v3 = msg2buf[i + 768];
        atomicAdd(&tile[p0 & 127], v0);
        atomicAdd(&tile[p1 & 127], v1);
        atomicAdd(&tile[p2 & 127], v2);
        atomicAdd(&tile[p3 & 127], v3);
    }
    for (; i < hi; i += 256) {
        atomicAdd(&tile[bucket_d[i] & 127], msg2buf[i]);
    }
    __syncthreads();
    if (t < RW) {
        int node = r * RW + t;
        if (node < N) out[node] = tile[t] * rsqrtf(fmaxf(deg_in[node], 1.f)) + b2[0];
    }
}

extern "C" void kernel_launch(void* const* d_in, const int* in_sizes, int n_in,
                              void* d_out, int out_size, void* d_ws, size_t ws_size,
                              hipStream_t stream) {
    const float* x  = (const float*)d_in[0];
    const int* src  = (const int*)d_in[1];
    const int* dst  = (const int*)d_in[2];
    const float* W1 = (const float*)d_in[3];
    const float* b1 = (const float*)d_in[4];
    const float* W2 = (const float*)d_in[5];
    const float* b2 = (const float*)d_in[6];
    float* out = (float*)d_out;

    const int N = out_size;      // 100000
    const int E = in_sizes[1];   // 3200000
    const int R = (N + RW - 1) / RW;                    // 782
    const int chunk = (((E + CCH - 1) / CCH) + 3) & ~3; // multiple of 4 for int4 loads

    // workspace layout (every region fully written before read each call; no memset)
    float* ws      = (float*)d_ws;
    float* deg_out = ws;                        // N
    float* deg_in  = deg_out + N;               // N
    int*   cnt_d   = (int*)(deg_in + N);        // CCH*R
    int*   cnt_s   = cnt_d + (size_t)CCH * R;   // CCH*R
    int*   tot_d   = cnt_s + (size_t)CCH * R;   // R
    int*   tot_s   = tot_d + R;                 // R
    int*   base_d  = tot_s + R;                 // R+1
    int*   base_s  = base_d + R + 1;            // R+1
    uint4* h4      = (uint4*)(((uintptr_t)(base_s + R + 1) + 15) & ~(uintptr_t)15); // N
    unsigned int* bucket_d  = (unsigned int*)(h4 + N);            // E
    unsigned int* bucket_sv = bucket_d + E;                       // E
    float*        msg2buf   = (float*)(bucket_sv + E);            // E
    uint4*        msgbuf    = (uint4*)(((uintptr_t)(msg2buf + E) + 15) & ~(uintptr_t)15); // E

    pass1_count<<<CCH, 256, 0, stream>>>(src, dst, cnt_d, cnt_s, E, R, chunk);
    scan1_kernel<<<dim3(R, 2), 256, 0, stream>>>(cnt_d, cnt_s, tot_d, tot_s, R);
    scan2_kernel<<<2, 256, 0, stream>>>(tot_d, tot_s, base_d, base_s, R);
    scatter_kernel<<<CCH, 256, 0, stream>>>(src, dst, cnt_d, cnt_s, base_d, base_s,
                                            bucket_d, bucket_sv, E, R, chunk);
    degout_kernel<<<R, 256, 0, stream>>>(bucket_sv, base_s, deg_out, N);
    conv1_kernel<<<(N + 31) / 32, 256, 0, stream>>>(x, W1, deg_out, h4, N);
    shuffle1_kernel<<<R, 256, 0, stream>>>(bucket_sv, base_s, h4, msgbuf, N);
    agg1_kernel<<<R, 256, 0, stream>>>(bucket_d, base_d, msgbuf, bucket_sv, base_s,
                                       deg_out, b1, W2, deg_in, msg2buf, N);
    agg2_kernel<<<R, 256, 0, stream>>>(bucket_d, base_d, msg2buf, deg_in, b2, out, N);
}

// Round 6
// 308.725 us; speedup vs baseline: 1.1756x; 1.1756x over previous
//
#include <hip/hip_runtime.h>
#include <hip/hip_bf16.h>
#include <hip/hip_fp16.h>

#define IN_DIM 128
#define HID 8
#define RW 128       // src-range width (sort A granularity)
#define MAXR 1024    // max src ranges
#define DTW 256      // dst-tile width (sort B granularity, agg block window)
#define MAXRD 512    // max dst tiles
#define CCH 512      // edge chunks
#define TP 257       // padded LDS tile stride (bank spread)

// ---------------- pass1A: per-chunk src-range histogram ----------------
__global__ __launch_bounds__(256) void pass1A_kernel(const int* __restrict__ src,
        int* __restrict__ cntA, int E, int R, int chunk) {
    __shared__ int cs[MAXR];
    int t = threadIdx.x, c = blockIdx.x;
    for (int i = t; i < R; i += 256) cs[i] = 0;
    __syncthreads();
    int lo = c * chunk, hi = min(lo + chunk, E);
    if (lo < hi) {
        const int4* s4 = reinterpret_cast<const int4*>(src);
        int q0 = lo >> 2, q1 = hi >> 2;
        for (int q = q0 + t; q < q1; q += 256) {
            int4 s = s4[q];
            atomicAdd(&cs[s.x >> 7], 1); atomicAdd(&cs[s.y >> 7], 1);
            atomicAdd(&cs[s.z >> 7], 1); atomicAdd(&cs[s.w >> 7], 1);
        }
        for (int i = (q1 << 2) + t; i < hi; i += 256) atomicAdd(&cs[src[i] >> 7], 1);
    }
    __syncthreads();
    for (int i = t; i < R; i += 256) cntA[(size_t)c * R + i] = cs[i];
}

// ---------------- scan1: per-bucket exclusive scan over 512 chunks (in place) + totals ----------------
__global__ __launch_bounds__(256) void scan1_kernel(int* __restrict__ cnt, int* __restrict__ tot, int R) {
    int r = blockIdx.x;
    __shared__ int sh[256];
    int t = threadIdx.x;
    int e0 = cnt[(size_t)(2 * t) * R + r];
    int e1 = cnt[(size_t)(2 * t + 1) * R + r];
    int s = e0 + e1;
    sh[t] = s;
    __syncthreads();
    for (int off = 1; off < 256; off <<= 1) {
        int v = (t >= off) ? sh[t - off] : 0;
        __syncthreads();
        sh[t] += v;
        __syncthreads();
    }
    int exc = sh[t] - s;
    cnt[(size_t)(2 * t) * R + r] = exc;
    cnt[(size_t)(2 * t + 1) * R + r] = exc + e0;
    if (t == 255) tot[r] = sh[255];
}

// ---------------- scan2: exclusive scan of bucket totals -> bases ----------------
__global__ __launch_bounds__(256) void scan2_kernel(const int* __restrict__ tot, int* __restrict__ base, int R) {
    __shared__ int sh[256];
    int t = threadIdx.x;
    int K = (R + 255) / 256;   // <=4
    int vals[4];
    int s = 0;
    for (int k = 0; k < K; ++k) {
        int i = t * K + k;
        int v = (i < R) ? tot[i] : 0;
        vals[k] = v; s += v;
    }
    sh[t] = s;
    __syncthreads();
    for (int off = 1; off < 256; off <<= 1) {
        int v = (t >= off) ? sh[t - off] : 0;
        __syncthreads();
        sh[t] += v;
        __syncthreads();
    }
    int exc = sh[t] - s;
    for (int k = 0; k < K; ++k) {
        int i = t * K + k;
        if (i < R) base[i] = exc;
        exc += vals[k];
    }
    if (t == 255) base[R] = sh[255];
}

// ---------------- scatterA: stable sort by src-range; 8B records (dst,src) ----------------
__global__ __launch_bounds__(256) void scatterA_kernel(const int* __restrict__ src, const int* __restrict__ dst,
        const int* __restrict__ cntA, const int* __restrict__ baseA,
        uint2* __restrict__ edge8, int E, int R, int chunk) {
    __shared__ int os[MAXR];
    int t = threadIdx.x, c = blockIdx.x;
    for (int i = t; i < R; i += 256) os[i] = baseA[i] + cntA[(size_t)c * R + i];
    __syncthreads();
    int lo = c * chunk, hi = min(lo + chunk, E);
    if (lo >= hi) return;
    const int4* s4 = reinterpret_cast<const int4*>(src);
    const int4* d4 = reinterpret_cast<const int4*>(dst);
    int q0 = lo >> 2, q1 = hi >> 2;
    for (int q = q0 + t; q < q1; q += 256) {
        int4 d = d4[q], s = s4[q];
        int p;
        p = atomicAdd(&os[s.x >> 7], 1); edge8[p] = make_uint2((unsigned)d.x, (unsigned)s.x);
        p = atomicAdd(&os[s.y >> 7], 1); edge8[p] = make_uint2((unsigned)d.y, (unsigned)s.y);
        p = atomicAdd(&os[s.z >> 7], 1); edge8[p] = make_uint2((unsigned)d.z, (unsigned)s.z);
        p = atomicAdd(&os[s.w >> 7], 1); edge8[p] = make_uint2((unsigned)d.w, (unsigned)s.w);
    }
    for (int i = (q1 << 2) + t; i < hi; i += 256) {
        int p = atomicAdd(&os[src[i] >> 7], 1);
        edge8[p] = make_uint2((unsigned)dst[i], (unsigned)src[i]);
    }
}

// ---------------- pass1B: per-chunk dst-tile histogram over src-sorted list ----------------
__global__ __launch_bounds__(256) void pass1B_kernel(const uint2* __restrict__ edge8,
        int* __restrict__ cntB, int E, int RD, int chunk) {
    __shared__ int cb[MAXRD];
    int t = threadIdx.x, c = blockIdx.x;
    for (int i = t; i < RD; i += 256) cb[i] = 0;
    __syncthreads();
    int lo = c * chunk, hi = min(lo + chunk, E);
    if (lo < hi) {
        const uint4* e2 = reinterpret_cast<const uint4*>(edge8);
        int q0 = lo >> 1, q1 = hi >> 1;
        for (int q = q0 + t; q < q1; q += 256) {
            uint4 v = e2[q];
            atomicAdd(&cb[v.x >> 8], 1);
            atomicAdd(&cb[v.z >> 8], 1);
        }
        for (int i = (q1 << 1) + t; i < hi; i += 256) atomicAdd(&cb[edge8[i].x >> 8], 1);
    }
    __syncthreads();
    for (int i = t; i < RD; i += 256) cntB[(size_t)c * RD + i] = cb[i];
}

// ---------------- scatterB: stable sort by dst-tile; 4B records (src<<8|dstloc) ----------------
__global__ __launch_bounds__(256) void scatterB_kernel(const uint2* __restrict__ edge8,
        const int* __restrict__ cntB, const int* __restrict__ baseB,
        unsigned int* __restrict__ bucketF, int E, int RD, int chunk) {
    __shared__ int ob[MAXRD];
    int t = threadIdx.x, c = blockIdx.x;
    for (int i = t; i < RD; i += 256) ob[i] = baseB[i] + cntB[(size_t)c * RD + i];
    __syncthreads();
    int lo = c * chunk, hi = min(lo + chunk, E);
    if (lo >= hi) return;
    const uint4* e2 = reinterpret_cast<const uint4*>(edge8);
    int q0 = lo >> 1, q1 = hi >> 1;
    for (int q = q0 + t; q < q1; q += 256) {
        uint4 v = e2[q];
        int p;
        p = atomicAdd(&ob[v.x >> 8], 1); bucketF[p] = (v.y << 8) | (v.x & 255u);
        p = atomicAdd(&ob[v.z >> 8], 1); bucketF[p] = (v.w << 8) | (v.z & 255u);
    }
    for (int i = (q1 << 1) + t; i < hi; i += 256) {
        uint2 v = edge8[i];
        int p = atomicAdd(&ob[v.x >> 8], 1);
        bucketF[p] = (v.y << 8) | (v.x & 255u);
    }
}

// ---------------- degout: per src-range count (sequential read of src-sorted list) ----------------
__global__ __launch_bounds__(256) void degout_kernel(const uint2* __restrict__ edge8,
        const int* __restrict__ baseA, float* __restrict__ deg_out, int N) {
    __shared__ int cnt[RW];
    int r = blockIdx.x, t = threadIdx.x;
    if (t < RW) cnt[t] = 0;
    __syncthreads();
    int lo = baseA[r], hi = baseA[r + 1];
    for (int i = lo + t; i < hi; i += 256) atomicAdd(&cnt[edge8[i].y & 127u], 1);
    __syncthreads();
    if (t < RW) {
        int node = r * RW + t;
        if (node < N) deg_out[node] = (float)cnt[t];
    }
}

// ---------------- conv1: h = (x * norm_out) @ W1, packed f16x8 (16B/node) ----------------
__global__ __launch_bounds__(256) void conv1_kernel(
        const float* __restrict__ x, const float* __restrict__ W1,
        const float* __restrict__ deg_out, uint4* __restrict__ h4, int N) {
    __shared__ float wt[HID * 132];
    int t = threadIdx.x;
    for (int i = t; i < IN_DIM * HID; i += 256) {
        int k = i >> 3, j = i & 7;
        wt[j * 132 + k] = W1[i];
    }
    __syncthreads();
    int grp = t >> 3, lane = t & 7;
    int node = blockIdx.x * 32 + grp;
    if (node >= N) return;
    const float4* xp = reinterpret_cast<const float4*>(x + (size_t)node * IN_DIM);
    float4 xv[4];
    #pragma unroll
    for (int m = 0; m < 4; ++m) xv[m] = xp[lane + m * 8];
    float acc[HID];
    #pragma unroll
    for (int j = 0; j < HID; ++j) acc[j] = 0.f;
    #pragma unroll
    for (int j = 0; j < HID; ++j) {
        #pragma unroll
        for (int m = 0; m < 4; ++m) {
            float4 wv = *reinterpret_cast<const float4*>(&wt[j * 132 + lane * 4 + m * 32]);
            acc[j] += xv[m].x * wv.x + xv[m].y * wv.y + xv[m].z * wv.z + xv[m].w * wv.w;
        }
    }
    #pragma unroll
    for (int off = 1; off < 8; off <<= 1) {
        #pragma unroll
        for (int j = 0; j < HID; ++j) acc[j] += __shfl_xor(acc[j], off, 64);
    }
    if (lane == 0) {
        float nrm = rsqrtf(fmaxf(deg_out[node], 1.0f));
        __half2 p0 = __floats2half2_rn(acc[0] * nrm, acc[1] * nrm);
        __half2 p1 = __floats2half2_rn(acc[2] * nrm, acc[3] * nrm);
        __half2 p2 = __floats2half2_rn(acc[4] * nrm, acc[5] * nrm);
        __half2 p3 = __floats2half2_rn(acc[6] * nrm, acc[7] * nrm);
        uint4 o;
        o.x = *reinterpret_cast<unsigned*>(&p0);
        o.y = *reinterpret_cast<unsigned*>(&p1);
        o.z = *reinterpret_cast<unsigned*>(&p2);
        o.w = *reinterpret_cast<unsigned*>(&p3);
        h4[node] = o;
    }
}

// ---------------- agg1F: per dst-tile, sequential bucket + monotone h4 gather ----------------
__device__ __forceinline__ void addEdge1(float* tile, int* cnt, unsigned p, uint4 g) {
    int l = p & 255;
    __half2 q0 = *reinterpret_cast<__half2*>(&g.x);
    __half2 q1 = *reinterpret_cast<__half2*>(&g.y);
    __half2 q2 = *reinterpret_cast<__half2*>(&g.z);
    __half2 q3 = *reinterpret_cast<__half2*>(&g.w);
    float2 f0 = __half22float2(q0), f1 = __half22float2(q1);
    float2 f2 = __half22float2(q2), f3 = __half22float2(q3);
    atomicAdd(&cnt[l], 1);
    atomicAdd(&tile[0 * TP + l], f0.x);
    atomicAdd(&tile[1 * TP + l], f0.y);
    atomicAdd(&tile[2 * TP + l], f1.x);
    atomicAdd(&tile[3 * TP + l], f1.y);
    atomicAdd(&tile[4 * TP + l], f2.x);
    atomicAdd(&tile[5 * TP + l], f2.y);
    atomicAdd(&tile[6 * TP + l], f3.x);
    atomicAdd(&tile[7 * TP + l], f3.y);
}

__global__ __launch_bounds__(512) void agg1F_kernel(const unsigned int* __restrict__ bucketF,
        const int* __restrict__ baseB, const uint4* __restrict__ h4,
        const float* __restrict__ deg_out, const float* __restrict__ b1, const float* __restrict__ W2,
        float* __restrict__ h2, float* __restrict__ deg_in, int N) {
    __shared__ float tile[HID * TP];
    __shared__ int cnt[DTW];
    int r = blockIdx.x, t = threadIdx.x;
    for (int i = t; i < HID * TP; i += 512) tile[i] = 0.f;
    if (t < DTW) cnt[t] = 0;
    __syncthreads();
    int lo = baseB[r], hi = baseB[r + 1];
    int i = lo + t;
    for (; i + 1536 < hi; i += 2048) {
        unsigned p0 = bucketF[i], p1 = bucketF[i + 512], p2 = bucketF[i + 1024], p3 = bucketF[i + 1536];
        uint4 g0 = h4[p0 >> 8], g1 = h4[p1 >> 8], g2 = h4[p2 >> 8], g3 = h4[p3 >> 8];
        addEdge1(tile, cnt, p0, g0);
        addEdge1(tile, cnt, p1, g1);
        addEdge1(tile, cnt, p2, g2);
        addEdge1(tile, cnt, p3, g3);
    }
    for (; i < hi; i += 512) {
        unsigned p = bucketF[i];
        uint4 g = h4[p >> 8];
        addEdge1(tile, cnt, p, g);
    }
    __syncthreads();
    if (t < DTW) {
        int node = r * DTW + t;
        if (node < N) {
            float din = (float)cnt[t];
            deg_in[node] = din;
            float nin = rsqrtf(fmaxf(din, 1.f));
            float nout = rsqrtf(fmaxf(deg_out[node], 1.f));
            float dot = 0.f;
            #pragma unroll
            for (int j = 0; j < HID; ++j) {
                float y = fmaxf(tile[j * TP + t] * nin + b1[j], 0.f);
                dot += y * W2[j];
            }
            h2[node] = dot * nout;
        }
    }
}

// ---------------- agg2F: per dst-tile, sequential bucket + monotone h2 gather ----------------
__global__ __launch_bounds__(512) void agg2F_kernel(const unsigned int* __restrict__ bucketF,
        const int* __restrict__ baseB, const float* __restrict__ h2,
        const float* __restrict__ deg_in, const float* __restrict__ b2,
        float* __restrict__ out, int N) {
    __shared__ float tile[DTW];
    int r = blockIdx.x, t = threadIdx.x;
    if (t < DTW) tile[t] = 0.f;
    __syncthreads();
    int lo = baseB[r], hi = baseB[r + 1];
    int i = lo + t;
    for (; i + 1536 < hi; i += 2048) {
        unsigned p0 = bucketF[i], p1 = bucketF[i + 512], p2 = bucketF[i + 1024], p3 = bucketF[i + 1536];
        float v0 = h2[p0 >> 8], v1 = h2[p1 >> 8], v2 = h2[p2 >> 8], v3 = h2[p3 >> 8];
        atomicAdd(&tile[p0 & 255u], v0);
        atomicAdd(&tile[p1 & 255u], v1);
        atomicAdd(&tile[p2 & 255u], v2);
        atomicAdd(&tile[p3 & 255u], v3);
    }
    for (; i < hi; i += 512) {
        unsigned p = bucketF[i];
        atomicAdd(&tile[p & 255u], h2[p >> 8]);
    }
    __syncthreads();
    if (t < DTW) {
        int node = r * DTW + t;
        if (node < N) out[node] = tile[t] * rsqrtf(fmaxf(deg_in[node], 1.f)) + b2[0];
    }
}

extern "C" void kernel_launch(void* const* d_in, const int* in_sizes, int n_in,
                              void* d_out, int out_size, void* d_ws, size_t ws_size,
                              hipStream_t stream) {
    const float* x  = (const float*)d_in[0];
    const int* src  = (const int*)d_in[1];
    const int* dst  = (const int*)d_in[2];
    const float* W1 = (const float*)d_in[3];
    const float* b1 = (const float*)d_in[4];
    const float* W2 = (const float*)d_in[5];
    const float* b2 = (const float*)d_in[6];
    float* out = (float*)d_out;

    const int N  = out_size;     // 100000
    const int E  = in_sizes[1];  // 3200000
    const int R  = (N + RW - 1) / RW;    // 782 src ranges
    const int RD = (N + DTW - 1) / DTW;  // 391 dst tiles
    const int chunkA = (((E + CCH - 1) / CCH) + 3) & ~3;  // mult of 4 (int4)
    const int chunkB = (((E + CCH - 1) / CCH) + 1) & ~1;  // mult of 2 (uint4 over uint2)

    // workspace layout (every region fully written before read each call; no memset)
    float* ws      = (float*)d_ws;
    float* deg_out = ws;                        // N
    float* deg_in  = deg_out + N;               // N
    float* h2      = deg_in + N;                // N
    int*   cntA    = (int*)(h2 + N);            // CCH*R
    int*   totA    = cntA + (size_t)CCH * R;    // R
    int*   baseA   = totA + R;                  // R+1
    int*   cntB    = baseA + R + 1;             // CCH*RD
    int*   totB    = cntB + (size_t)CCH * RD;   // RD
    int*   baseB   = totB + RD;                 // RD+1
    unsigned int* bucketF = (unsigned int*)(baseB + RD + 1);  // E
    uint4* h4     = (uint4*)(((uintptr_t)(bucketF + E) + 15) & ~(uintptr_t)15);  // N
    uint2* edge8  = (uint2*)(h4 + N);           // E (16B-aligned since h4 aligned)

    pass1A_kernel<<<CCH, 256, 0, stream>>>(src, cntA, E, R, chunkA);
    scan1_kernel<<<R, 256, 0, stream>>>(cntA, totA, R);
    scan2_kernel<<<1, 256, 0, stream>>>(totA, baseA, R);
    scatterA_kernel<<<CCH, 256, 0, stream>>>(src, dst, cntA, baseA, edge8, E, R, chunkA);
    pass1B_kernel<<<CCH, 256, 0, stream>>>(edge8, cntB, E, RD, chunkB);
    scan1_kernel<<<RD, 256, 0, stream>>>(cntB, totB, RD);
    scan2_kernel<<<1, 256, 0, stream>>>(totB, baseB, RD);
    scatterB_kernel<<<CCH, 256, 0, stream>>>(edge8, cntB, baseB, bucketF, E, RD, chunkB);
    degout_kernel<<<R, 256, 0, stream>>>(edge8, baseA, deg_out, N);
    conv1_kernel<<<(N + 31) / 32, 256, 0, stream>>>(x, W1, deg_out, h4, N);
    agg1F_kernel<<<RD, 512, 0, stream>>>(bucketF, baseB, h4, deg_out, b1, W2, h2, deg_in, N);
    agg2F_kernel<<<RD, 512, 0, stream>>>(bucketF, baseB, h2, deg_in, b2, out, N);
}

// Round 7
// 159.121 us; speedup vs baseline: 2.2810x; 1.9402x over previous
//
#include <hip/hip_runtime.h>
#include <hip/hip_bf16.h>
#include <hip/hip_fp16.h>

#define IN_DIM 128
#define HID 8
#define TW 256       // node tile width (both src and dst sides)
#define MAXT 512     // max tiles (N<=131072)
#define CCH 512      // edge chunks

// ---------------- pass1AB: per-chunk src-tile AND dst-tile histograms ----------------
__global__ __launch_bounds__(256) void pass1AB_kernel(const int* __restrict__ src, const int* __restrict__ dst,
        int* __restrict__ cntS, int* __restrict__ cntD, int E, int RT, int chunk) {
    __shared__ int cs[MAXT], cd[MAXT];
    int t = threadIdx.x, c = blockIdx.x;
    for (int i = t; i < RT; i += 256) { cs[i] = 0; cd[i] = 0; }
    __syncthreads();
    int lo = c * chunk, hi = min(lo + chunk, E);
    if (lo < hi) {
        const int4* s4 = reinterpret_cast<const int4*>(src);
        const int4* d4 = reinterpret_cast<const int4*>(dst);
        int q0 = lo >> 2, q1 = hi >> 2;
        for (int q = q0 + t; q < q1; q += 256) {
            int4 s = s4[q], d = d4[q];
            atomicAdd(&cs[s.x >> 8], 1); atomicAdd(&cs[s.y >> 8], 1);
            atomicAdd(&cs[s.z >> 8], 1); atomicAdd(&cs[s.w >> 8], 1);
            atomicAdd(&cd[d.x >> 8], 1); atomicAdd(&cd[d.y >> 8], 1);
            atomicAdd(&cd[d.z >> 8], 1); atomicAdd(&cd[d.w >> 8], 1);
        }
        for (int i = (q1 << 2) + t; i < hi; i += 256) {
            atomicAdd(&cs[src[i] >> 8], 1);
            atomicAdd(&cd[dst[i] >> 8], 1);
        }
    }
    __syncthreads();
    for (int i = t; i < RT; i += 256) {
        cntS[(size_t)c * RT + i] = cs[i];
        cntD[(size_t)c * RT + i] = cd[i];
    }
}

// ---------------- scan1: per-tile exclusive scan over 512 chunks (in place) + totals ----------------
__global__ __launch_bounds__(256) void scan1_kernel(int* __restrict__ cnt, int* __restrict__ tot, int R) {
    int r = blockIdx.x;
    __shared__ int sh[256];
    int t = threadIdx.x;
    int e0 = cnt[(size_t)(2 * t) * R + r];
    int e1 = cnt[(size_t)(2 * t + 1) * R + r];
    int s = e0 + e1;
    sh[t] = s;
    __syncthreads();
    for (int off = 1; off < 256; off <<= 1) {
        int v = (t >= off) ? sh[t - off] : 0;
        __syncthreads();
        sh[t] += v;
        __syncthreads();
    }
    int exc = sh[t] - s;
    cnt[(size_t)(2 * t) * R + r] = exc;
    cnt[(size_t)(2 * t + 1) * R + r] = exc + e0;
    if (t == 255) tot[r] = sh[255];
}

// ---------------- scan2: exclusive scan of tile totals -> bases ----------------
__global__ __launch_bounds__(256) void scan2_kernel(const int* __restrict__ tot, int* __restrict__ base, int R) {
    __shared__ int sh[256];
    int t = threadIdx.x;
    int K = (R + 255) / 256;   // <=2
    int vals[4];
    int s = 0;
    for (int k = 0; k < K; ++k) {
        int i = t * K + k;
        int v = (i < R) ? tot[i] : 0;
        vals[k] = v; s += v;
    }
    sh[t] = s;
    __syncthreads();
    for (int off = 1; off < 256; off <<= 1) {
        int v = (t >= off) ? sh[t - off] : 0;
        __syncthreads();
        sh[t] += v;
        __syncthreads();
    }
    int exc = sh[t] - s;
    for (int k = 0; k < K; ++k) {
        int i = t * K + k;
        if (i < R) base[i] = exc;
        exc += vals[k];
    }
    if (t == 255) base[R] = sh[255];
}

// ---------------- scatterAB: src-tile byte locals + dst-tile packed records ----------------
__global__ __launch_bounds__(256) void scatterAB_kernel(const int* __restrict__ src, const int* __restrict__ dst,
        const int* __restrict__ cntS, const int* __restrict__ cntD,
        const int* __restrict__ baseS, const int* __restrict__ baseD,
        unsigned char* __restrict__ bucket_s, unsigned int* __restrict__ bucketT,
        int E, int RT, int chunk) {
    __shared__ int os[MAXT], od[MAXT];
    int t = threadIdx.x, c = blockIdx.x;
    for (int i = t; i < RT; i += 256) {
        os[i] = baseS[i] + cntS[(size_t)c * RT + i];
        od[i] = baseD[i] + cntD[(size_t)c * RT + i];
    }
    __syncthreads();
    int lo = c * chunk, hi = min(lo + chunk, E);
    if (lo >= hi) return;
    const int4* s4 = reinterpret_cast<const int4*>(src);
    const int4* d4 = reinterpret_cast<const int4*>(dst);
    int q0 = lo >> 2, q1 = hi >> 2;
    for (int q = q0 + t; q < q1; q += 256) {
        int4 s = s4[q], d = d4[q];
        int p;
        p = atomicAdd(&os[s.x >> 8], 1); bucket_s[p] = (unsigned char)(s.x & 255);
        p = atomicAdd(&os[s.y >> 8], 1); bucket_s[p] = (unsigned char)(s.y & 255);
        p = atomicAdd(&os[s.z >> 8], 1); bucket_s[p] = (unsigned char)(s.z & 255);
        p = atomicAdd(&os[s.w >> 8], 1); bucket_s[p] = (unsigned char)(s.w & 255);
        p = atomicAdd(&od[d.x >> 8], 1); bucketT[p] = ((unsigned)s.x << 8) | (unsigned)(d.x & 255);
        p = atomicAdd(&od[d.y >> 8], 1); bucketT[p] = ((unsigned)s.y << 8) | (unsigned)(d.y & 255);
        p = atomicAdd(&od[d.z >> 8], 1); bucketT[p] = ((unsigned)s.z << 8) | (unsigned)(d.z & 255);
        p = atomicAdd(&od[d.w >> 8], 1); bucketT[p] = ((unsigned)s.w << 8) | (unsigned)(d.w & 255);
    }
    for (int i = (q1 << 2) + t; i < hi; i += 256) {
        int s = src[i], d = dst[i];
        int p = atomicAdd(&os[s >> 8], 1);
        bucket_s[p] = (unsigned char)(s & 255);
        p = atomicAdd(&od[d >> 8], 1);
        bucketT[p] = ((unsigned)s << 8) | (unsigned)(d & 255);
    }
}

// ---------------- degout: per src-tile node counts (word reads of byte locals) ----------------
__global__ __launch_bounds__(256) void degout_kernel(const unsigned char* __restrict__ bucket_s,
        const int* __restrict__ baseS, float* __restrict__ deg_out, int N) {
    __shared__ int cnt[TW];
    int r = blockIdx.x, t = threadIdx.x;
    cnt[t] = 0;
    __syncthreads();
    int lo = baseS[r], hi = baseS[r + 1];
    int a0 = min((lo + 3) & ~3, hi), a1 = max(hi & ~3, a0);
    for (int i = lo + t; i < a0; i += 256) atomicAdd(&cnt[bucket_s[i]], 1);
    const unsigned* w4 = reinterpret_cast<const unsigned*>(bucket_s);
    for (int q = (a0 >> 2) + t; q < (a1 >> 2); q += 256) {
        unsigned w = w4[q];
        atomicAdd(&cnt[w & 255], 1);
        atomicAdd(&cnt[(w >> 8) & 255], 1);
        atomicAdd(&cnt[(w >> 16) & 255], 1);
        atomicAdd(&cnt[w >> 24], 1);
    }
    for (int i = a1 + t; i < hi; i += 256) atomicAdd(&cnt[bucket_s[i]], 1);
    __syncthreads();
    int node = r * TW + t;
    if (node < N) deg_out[node] = (float)cnt[t];
}

// ---------------- passC: full sort within dst-tile -> bucketG (src ids) + CSR row_ptr ----------------
__global__ __launch_bounds__(512) void passC_kernel(const unsigned int* __restrict__ bucketT,
        const int* __restrict__ baseD, unsigned int* __restrict__ bucketG,
        int* __restrict__ row_ptr, int E, int RT) {
    __shared__ int cnt[TW];
    __shared__ int scn[TW];
    __shared__ int start[TW];
    int r = blockIdx.x, t = threadIdx.x;
    if (t < TW) cnt[t] = 0;
    __syncthreads();
    int lo = baseD[r], hi = baseD[r + 1];
    for (int i = lo + t; i < hi; i += 512) atomicAdd(&cnt[bucketT[i] & 255u], 1);
    __syncthreads();
    if (t < TW) scn[t] = cnt[t];
    __syncthreads();
    for (int off = 1; off < TW; off <<= 1) {
        int v = 0;
        if (t < TW && t >= off) v = scn[t - off];
        __syncthreads();
        if (t < TW) scn[t] += v;
        __syncthreads();
    }
    if (t < TW) {
        int ex = scn[t] - cnt[t];
        start[t] = ex;
        row_ptr[r * TW + t] = lo + ex;
    }
    if (r == 0 && t == 0) row_ptr[RT * TW] = E;
    __syncthreads();
    for (int i = lo + t; i < hi; i += 512) {
        unsigned v = bucketT[i];
        int p = atomicAdd(&start[v & 255u], 1);
        bucketG[lo + p] = v >> 8;
    }
}

// ---------------- conv1: h = (x * norm_out) @ W1, packed f16x8 (16B/node) ----------------
__global__ __launch_bounds__(256) void conv1_kernel(
        const float* __restrict__ x, const float* __restrict__ W1,
        const float* __restrict__ deg_out, uint4* __restrict__ h4, int N) {
    __shared__ float wt[HID * 132];
    int t = threadIdx.x;
    for (int i = t; i < IN_DIM * HID; i += 256) {
        int k = i >> 3, j = i & 7;
        wt[j * 132 + k] = W1[i];
    }
    __syncthreads();
    int grp = t >> 3, lane = t & 7;
    int node = blockIdx.x * 32 + grp;
    if (node >= N) return;
    const float4* xp = reinterpret_cast<const float4*>(x + (size_t)node * IN_DIM);
    float4 xv[4];
    #pragma unroll
    for (int m = 0; m < 4; ++m) xv[m] = xp[lane + m * 8];
    float acc[HID];
    #pragma unroll
    for (int j = 0; j < HID; ++j) acc[j] = 0.f;
    #pragma unroll
    for (int j = 0; j < HID; ++j) {
        #pragma unroll
        for (int m = 0; m < 4; ++m) {
            float4 wv = *reinterpret_cast<const float4*>(&wt[j * 132 + lane * 4 + m * 32]);
            acc[j] += xv[m].x * wv.x + xv[m].y * wv.y + xv[m].z * wv.z + xv[m].w * wv.w;
        }
    }
    #pragma unroll
    for (int off = 1; off < 8; off <<= 1) {
        #pragma unroll
        for (int j = 0; j < HID; ++j) acc[j] += __shfl_xor(acc[j], off, 64);
    }
    if (lane == 0) {
        float nrm = rsqrtf(fmaxf(deg_out[node], 1.0f));
        __half2 p0 = __floats2half2_rn(acc[0] * nrm, acc[1] * nrm);
        __half2 p1 = __floats2half2_rn(acc[2] * nrm, acc[3] * nrm);
        __half2 p2 = __floats2half2_rn(acc[4] * nrm, acc[5] * nrm);
        __half2 p3 = __floats2half2_rn(acc[6] * nrm, acc[7] * nrm);
        uint4 o;
        o.x = *reinterpret_cast<unsigned*>(&p0);
        o.y = *reinterpret_cast<unsigned*>(&p1);
        o.z = *reinterpret_cast<unsigned*>(&p2);
        o.w = *reinterpret_cast<unsigned*>(&p3);
        h4[node] = o;
    }
}

// ---------------- agg1G: lane-per-node CSR, register accumulation, fused finalize -> h2 ----------------
__device__ __forceinline__ void accAdd(float* acc, uint4 g) {
    __half2 q0 = *reinterpret_cast<__half2*>(&g.x);
    __half2 q1 = *reinterpret_cast<__half2*>(&g.y);
    __half2 q2 = *reinterpret_cast<__half2*>(&g.z);
    __half2 q3 = *reinterpret_cast<__half2*>(&g.w);
    float2 f0 = __half22float2(q0), f1 = __half22float2(q1);
    float2 f2 = __half22float2(q2), f3 = __half22float2(q3);
    acc[0] += f0.x; acc[1] += f0.y;
    acc[2] += f1.x; acc[3] += f1.y;
    acc[4] += f2.x; acc[5] += f2.y;
    acc[6] += f3.x; acc[7] += f3.y;
}

__global__ __launch_bounds__(256) void agg1G_kernel(const unsigned int* __restrict__ bucketG,
        const int* __restrict__ row_ptr, const uint4* __restrict__ h4,
        const float* __restrict__ deg_out, const float* __restrict__ b1, const float* __restrict__ W2,
        float* __restrict__ h2, int N) {
    int node = blockIdx.x * 256 + threadIdx.x;
    int s0 = row_ptr[node], s1 = row_ptr[node + 1];
    float acc[HID];
    #pragma unroll
    for (int j = 0; j < HID; ++j) acc[j] = 0.f;
    int e = s0;
    for (; e + 4 <= s1; e += 4) {
        unsigned a = bucketG[e], b = bucketG[e + 1], c = bucketG[e + 2], d = bucketG[e + 3];
        uint4 g0 = h4[a], g1 = h4[b], g2 = h4[c], g3 = h4[d];
        accAdd(acc, g0); accAdd(acc, g1); accAdd(acc, g2); accAdd(acc, g3);
    }
    for (; e < s1; ++e) accAdd(acc, h4[bucketG[e]]);
    if (node < N) {
        float din = (float)(s1 - s0);
        float nin = rsqrtf(fmaxf(din, 1.f));
        float nout = rsqrtf(fmaxf(deg_out[node], 1.f));
        float dot = 0.f;
        #pragma unroll
        for (int j = 0; j < HID; ++j) {
            float y = fmaxf(acc[j] * nin + b1[j], 0.f);
            dot += y * W2[j];
        }
        h2[node] = dot * nout;
    }
}

// ---------------- agg2G: lane-per-node CSR over h2, fused final output ----------------
__global__ __launch_bounds__(256) void agg2G_kernel(const unsigned int* __restrict__ bucketG,
        const int* __restrict__ row_ptr, const float* __restrict__ h2,
        const float* __restrict__ b2, float* __restrict__ out, int N) {
    int node = blockIdx.x * 256 + threadIdx.x;
    int s0 = row_ptr[node], s1 = row_ptr[node + 1];
    float a = 0.f;
    int e = s0;
    for (; e + 4 <= s1; e += 4) {
        float v0 = h2[bucketG[e]], v1 = h2[bucketG[e + 1]];
        float v2 = h2[bucketG[e + 2]], v3 = h2[bucketG[e + 3]];
        a += (v0 + v1) + (v2 + v3);
    }
    for (; e < s1; ++e) a += h2[bucketG[e]];
    if (node < N) {
        float nin = rsqrtf(fmaxf((float)(s1 - s0), 1.f));
        out[node] = a * nin + b2[0];
    }
}

extern "C" void kernel_launch(void* const* d_in, const int* in_sizes, int n_in,
                              void* d_out, int out_size, void* d_ws, size_t ws_size,
                              hipStream_t stream) {
    const float* x  = (const float*)d_in[0];
    const int* src  = (const int*)d_in[1];
    const int* dst  = (const int*)d_in[2];
    const float* W1 = (const float*)d_in[3];
    const float* b1 = (const float*)d_in[4];
    const float* W2 = (const float*)d_in[5];
    const float* b2 = (const float*)d_in[6];
    float* out = (float*)d_out;

    const int N  = out_size;     // 100000
    const int E  = in_sizes[1];  // 3200000
    const int RT = (N + TW - 1) / TW;                 // 391 tiles
    const int chunk = (((E + CCH - 1) / CCH) + 3) & ~3;  // mult of 4 (int4)

    // workspace layout (every region fully written before read each call; no memset)
    float* ws      = (float*)d_ws;
    float* deg_out = ws;                        // N
    float* h2      = deg_out + N;               // N
    int*   cntS    = (int*)(h2 + N);            // CCH*RT
    int*   cntD    = cntS + (size_t)CCH * RT;   // CCH*RT
    int*   totS    = cntD + (size_t)CCH * RT;   // RT
    int*   baseS   = totS + RT;                 // RT+1
    int*   totD    = baseS + RT + 1;            // RT
    int*   baseD   = totD + RT;                 // RT+1
    int*   row_ptr = baseD + RT + 1;            // RT*TW+1
    unsigned int* bucketT = (unsigned int*)(row_ptr + (size_t)RT * TW + 1);  // E
    unsigned int* bucketG = bucketT + E;        // E
    uint4* h4 = (uint4*)(((uintptr_t)(bucketG + E) + 15) & ~(uintptr_t)15);  // N
    unsigned char* bucket_s = (unsigned char*)(h4 + N);  // E bytes

    pass1AB_kernel<<<CCH, 256, 0, stream>>>(src, dst, cntS, cntD, E, RT, chunk);
    scan1_kernel<<<RT, 256, 0, stream>>>(cntS, totS, RT);
    scan1_kernel<<<RT, 256, 0, stream>>>(cntD, totD, RT);
    scan2_kernel<<<1, 256, 0, stream>>>(totS, baseS, RT);
    scan2_kernel<<<1, 256, 0, stream>>>(totD, baseD, RT);
    scatterAB_kernel<<<CCH, 256, 0, stream>>>(src, dst, cntS, cntD, baseS, baseD,
                                              bucket_s, bucketT, E, RT, chunk);
    degout_kernel<<<RT, 256, 0, stream>>>(bucket_s, baseS, deg_out, N);
    passC_kernel<<<RT, 512, 0, stream>>>(bucketT, baseD, bucketG, row_ptr, E, RT);
    conv1_kernel<<<(N + 31) / 32, 256, 0, stream>>>(x, W1, deg_out, h4, N);
    agg1G_kernel<<<RT, 256, 0, stream>>>(bucketG, row_ptr, h4, deg_out, b1, W2, h2, N);
    agg2G_kernel<<<RT, 256, 0, stream>>>(bucketG, row_ptr, h2, b2, out, N);
}

// Round 8
// 135.220 us; speedup vs baseline: 2.6841x; 1.1768x over previous
//
#include <hip/hip_runtime.h>
#include <hip/hip_bf16.h>
#include <hip/hip_fp16.h>

#define IN_DIM 128
#define HID 8
#define TW 256       // node tile width (sort + CSR granularity)
#define MAXT 512     // max tiles (N<=131072)
#define CCH 256      // edge chunks (one 1024-thread block each)

// ---------------- pass1AB: per-chunk src-tile AND dst-tile histograms ----------------
__global__ __launch_bounds__(1024) void pass1AB_kernel(const int* __restrict__ src, const int* __restrict__ dst,
        int* __restrict__ cntS, int* __restrict__ cntD, int E, int RT, int chunk) {
    __shared__ int cs[MAXT], cd[MAXT];
    int t = threadIdx.x, c = blockIdx.x;
    for (int i = t; i < RT; i += 1024) { cs[i] = 0; cd[i] = 0; }
    __syncthreads();
    int lo = c * chunk, hi = min(lo + chunk, E);
    if (lo < hi) {
        const int4* s4 = reinterpret_cast<const int4*>(src);
        const int4* d4 = reinterpret_cast<const int4*>(dst);
        int q0 = lo >> 2, q1 = hi >> 2;
        for (int q = q0 + t; q < q1; q += 1024) {
            int4 s = s4[q], d = d4[q];
            atomicAdd(&cs[s.x >> 8], 1); atomicAdd(&cs[s.y >> 8], 1);
            atomicAdd(&cs[s.z >> 8], 1); atomicAdd(&cs[s.w >> 8], 1);
            atomicAdd(&cd[d.x >> 8], 1); atomicAdd(&cd[d.y >> 8], 1);
            atomicAdd(&cd[d.z >> 8], 1); atomicAdd(&cd[d.w >> 8], 1);
        }
        for (int i = (q1 << 2) + t; i < hi; i += 1024) {
            atomicAdd(&cs[src[i] >> 8], 1);
            atomicAdd(&cd[dst[i] >> 8], 1);
        }
    }
    __syncthreads();
    for (int i = t; i < RT; i += 1024) {
        cntS[(size_t)c * RT + i] = cs[i];
        cntD[(size_t)c * RT + i] = cd[i];
    }
}

// ---------------- scan1: per-tile exclusive scan over 256 chunks (S and D via blockIdx.y) ----------------
__global__ __launch_bounds__(256) void scan1_kernel(int* __restrict__ cntS, int* __restrict__ cntD,
        int* __restrict__ totS, int* __restrict__ totD, int RT) {
    int r = blockIdx.x;
    int* cnt = blockIdx.y ? cntD : cntS;
    int* tot = blockIdx.y ? totD : totS;
    __shared__ int sh[256];
    int t = threadIdx.x;
    int e = cnt[(size_t)t * RT + r];
    sh[t] = e;
    __syncthreads();
    for (int off = 1; off < 256; off <<= 1) {
        int v = (t >= off) ? sh[t - off] : 0;
        __syncthreads();
        sh[t] += v;
        __syncthreads();
    }
    cnt[(size_t)t * RT + r] = sh[t] - e;
    if (t == 255) tot[r] = sh[255];
}

// ---------------- scan2: exclusive scan of tile totals -> bases (S and D via blockIdx.x) ----------------
__global__ __launch_bounds__(256) void scan2_kernel(const int* __restrict__ totS, const int* __restrict__ totD,
        int* __restrict__ baseS, int* __restrict__ baseD, int RT) {
    const int* tot = blockIdx.x ? totD : totS;
    int* base = blockIdx.x ? baseD : baseS;
    __shared__ int sh[256];
    int t = threadIdx.x;
    int K = (RT + 255) / 256;   // <=2
    int vals[4];
    int s = 0;
    for (int k = 0; k < K; ++k) {
        int i = t * K + k;
        int v = (i < RT) ? tot[i] : 0;
        vals[k] = v; s += v;
    }
    sh[t] = s;
    __syncthreads();
    for (int off = 1; off < 256; off <<= 1) {
        int v = (t >= off) ? sh[t - off] : 0;
        __syncthreads();
        sh[t] += v;
        __syncthreads();
    }
    int exc = sh[t] - s;
    for (int k = 0; k < K; ++k) {
        int i = t * K + k;
        if (i < RT) base[i] = exc;
        exc += vals[k];
    }
    if (t == 255) base[RT] = sh[255];
}

// ---------------- scatterAB: src-tile byte locals + dst-tile packed records ----------------
__global__ __launch_bounds__(1024) void scatterAB_kernel(const int* __restrict__ src, const int* __restrict__ dst,
        const int* __restrict__ cntS, const int* __restrict__ cntD,
        const int* __restrict__ baseS, const int* __restrict__ baseD,
        unsigned char* __restrict__ bucket_s, unsigned int* __restrict__ bucketT,
        int E, int RT, int chunk) {
    __shared__ int os[MAXT], od[MAXT];
    int t = threadIdx.x, c = blockIdx.x;
    for (int i = t; i < RT; i += 1024) {
        os[i] = baseS[i] + cntS[(size_t)c * RT + i];
        od[i] = baseD[i] + cntD[(size_t)c * RT + i];
    }
    __syncthreads();
    int lo = c * chunk, hi = min(lo + chunk, E);
    if (lo >= hi) return;
    const int4* s4 = reinterpret_cast<const int4*>(src);
    const int4* d4 = reinterpret_cast<const int4*>(dst);
    int q0 = lo >> 2, q1 = hi >> 2;
    for (int q = q0 + t; q < q1; q += 1024) {
        int4 s = s4[q], d = d4[q];
        int p;
        p = atomicAdd(&os[s.x >> 8], 1); bucket_s[p] = (unsigned char)(s.x & 255);
        p = atomicAdd(&os[s.y >> 8], 1); bucket_s[p] = (unsigned char)(s.y & 255);
        p = atomicAdd(&os[s.z >> 8], 1); bucket_s[p] = (unsigned char)(s.z & 255);
        p = atomicAdd(&os[s.w >> 8], 1); bucket_s[p] = (unsigned char)(s.w & 255);
        p = atomicAdd(&od[d.x >> 8], 1); bucketT[p] = ((unsigned)s.x << 8) | (unsigned)(d.x & 255);
        p = atomicAdd(&od[d.y >> 8], 1); bucketT[p] = ((unsigned)s.y << 8) | (unsigned)(d.y & 255);
        p = atomicAdd(&od[d.z >> 8], 1); bucketT[p] = ((unsigned)s.z << 8) | (unsigned)(d.z & 255);
        p = atomicAdd(&od[d.w >> 8], 1); bucketT[p] = ((unsigned)s.w << 8) | (unsigned)(d.w & 255);
    }
    for (int i = (q1 << 2) + t; i < hi; i += 1024) {
        int s = src[i], d = dst[i];
        int p = atomicAdd(&os[s >> 8], 1);
        bucket_s[p] = (unsigned char)(s & 255);
        p = atomicAdd(&od[d >> 8], 1);
        bucketT[p] = ((unsigned)s << 8) | (unsigned)(d & 255);
    }
}

// ---------------- degout: per src-tile node counts (word reads of byte locals) ----------------
__global__ __launch_bounds__(256) void degout_kernel(const unsigned char* __restrict__ bucket_s,
        const int* __restrict__ baseS, float* __restrict__ deg_out, int N) {
    __shared__ int cnt[TW];
    int r = blockIdx.x, t = threadIdx.x;
    cnt[t] = 0;
    __syncthreads();
    int lo = baseS[r], hi = baseS[r + 1];
    int a0 = min((lo + 3) & ~3, hi), a1 = max(hi & ~3, a0);
    for (int i = lo + t; i < a0; i += 256) atomicAdd(&cnt[bucket_s[i]], 1);
    const unsigned* w4 = reinterpret_cast<const unsigned*>(bucket_s);
    for (int q = (a0 >> 2) + t; q < (a1 >> 2); q += 256) {
        unsigned w = w4[q];
        atomicAdd(&cnt[w & 255], 1);
        atomicAdd(&cnt[(w >> 8) & 255], 1);
        atomicAdd(&cnt[(w >> 16) & 255], 1);
        atomicAdd(&cnt[w >> 24], 1);
    }
    for (int i = a1 + t; i < hi; i += 256) atomicAdd(&cnt[bucket_s[i]], 1);
    __syncthreads();
    int node = r * TW + t;
    if (node < N) deg_out[node] = (float)cnt[t];
}

// ---------------- passC: full sort within dst-tile -> bucketG (src ids) + CSR row_ptr ----------------
__global__ __launch_bounds__(512) void passC_kernel(const unsigned int* __restrict__ bucketT,
        const int* __restrict__ baseD, unsigned int* __restrict__ bucketG,
        int* __restrict__ row_ptr, int E, int RT) {
    __shared__ int cnt[TW];
    __shared__ int scn[TW];
    __shared__ int start[TW];
    int r = blockIdx.x, t = threadIdx.x;
    if (t < TW) cnt[t] = 0;
    __syncthreads();
    int lo = baseD[r], hi = baseD[r + 1];
    for (int i = lo + t; i < hi; i += 512) atomicAdd(&cnt[bucketT[i] & 255u], 1);
    __syncthreads();
    if (t < TW) scn[t] = cnt[t];
    __syncthreads();
    for (int off = 1; off < TW; off <<= 1) {
        int v = 0;
        if (t < TW && t >= off) v = scn[t - off];
        __syncthreads();
        if (t < TW) scn[t] += v;
        __syncthreads();
    }
    if (t < TW) {
        int ex = scn[t] - cnt[t];
        start[t] = ex;
        row_ptr[r * TW + t] = lo + ex;
    }
    if (r == 0 && t == 0) row_ptr[RT * TW] = E;
    __syncthreads();
    for (int i = lo + t; i < hi; i += 512) {
        unsigned v = bucketT[i];
        int p = atomicAdd(&start[v & 255u], 1);
        bucketG[lo + p] = v >> 8;
    }
}

// ---------------- conv1: h = (x * norm_out) @ W1, packed f16x8 (16B/node) ----------------
__global__ __launch_bounds__(256) void conv1_kernel(
        const float* __restrict__ x, const float* __restrict__ W1,
        const float* __restrict__ deg_out, uint4* __restrict__ h4, int N) {
    __shared__ float wt[HID * 132];
    int t = threadIdx.x;
    for (int i = t; i < IN_DIM * HID; i += 256) {
        int k = i >> 3, j = i & 7;
        wt[j * 132 + k] = W1[i];
    }
    __syncthreads();
    int grp = t >> 3, lane = t & 7;
    int node = blockIdx.x * 32 + grp;
    if (node >= N) return;
    const float4* xp = reinterpret_cast<const float4*>(x + (size_t)node * IN_DIM);
    float4 xv[4];
    #pragma unroll
    for (int m = 0; m < 4; ++m) xv[m] = xp[lane + m * 8];
    float acc[HID];
    #pragma unroll
    for (int j = 0; j < HID; ++j) acc[j] = 0.f;
    #pragma unroll
    for (int j = 0; j < HID; ++j) {
        #pragma unroll
        for (int m = 0; m < 4; ++m) {
            float4 wv = *reinterpret_cast<const float4*>(&wt[j * 132 + lane * 4 + m * 32]);
            acc[j] += xv[m].x * wv.x + xv[m].y * wv.y + xv[m].z * wv.z + xv[m].w * wv.w;
        }
    }
    #pragma unroll
    for (int off = 1; off < 8; off <<= 1) {
        #pragma unroll
        for (int j = 0; j < HID; ++j) acc[j] += __shfl_xor(acc[j], off, 64);
    }
    if (lane == 0) {
        float nrm = rsqrtf(fmaxf(deg_out[node], 1.0f));
        __half2 p0 = __floats2half2_rn(acc[0] * nrm, acc[1] * nrm);
        __half2 p1 = __floats2half2_rn(acc[2] * nrm, acc[3] * nrm);
        __half2 p2 = __floats2half2_rn(acc[4] * nrm, acc[5] * nrm);
        __half2 p3 = __floats2half2_rn(acc[6] * nrm, acc[7] * nrm);
        uint4 o;
        o.x = *reinterpret_cast<unsigned*>(&p0);
        o.y = *reinterpret_cast<unsigned*>(&p1);
        o.z = *reinterpret_cast<unsigned*>(&p2);
        o.w = *reinterpret_cast<unsigned*>(&p3);
        h4[node] = o;
    }
}

// ---------------- agg1G4: 4 lanes per node, register accumulation, fused finalize -> h2 ----------------
__device__ __forceinline__ void accAdd(float* acc, uint4 g) {
    __half2 q0 = *reinterpret_cast<__half2*>(&g.x);
    __half2 q1 = *reinterpret_cast<__half2*>(&g.y);
    __half2 q2 = *reinterpret_cast<__half2*>(&g.z);
    __half2 q3 = *reinterpret_cast<__half2*>(&g.w);
    float2 f0 = __half22float2(q0), f1 = __half22float2(q1);
    float2 f2 = __half22float2(q2), f3 = __half22float2(q3);
    acc[0] += f0.x; acc[1] += f0.y;
    acc[2] += f1.x; acc[3] += f1.y;
    acc[4] += f2.x; acc[5] += f2.y;
    acc[6] += f3.x; acc[7] += f3.y;
}

__global__ __launch_bounds__(256) void agg1G4_kernel(const unsigned int* __restrict__ bucketG,
        const int* __restrict__ row_ptr, const uint4* __restrict__ h4,
        const float* __restrict__ deg_out, const float* __restrict__ b1, const float* __restrict__ W2,
        float* __restrict__ h2, int N) {
    int tid = blockIdx.x * 256 + threadIdx.x;
    int node = tid >> 2, sub = tid & 3;
    int s0 = row_ptr[node], s1 = row_ptr[node + 1];
    float acc[HID];
    #pragma unroll
    for (int j = 0; j < HID; ++j) acc[j] = 0.f;
    for (int e = s0 + sub; e < s1; e += 4) accAdd(acc, h4[bucketG[e]]);
    #pragma unroll
    for (int off = 1; off < 4; off <<= 1) {
        #pragma unroll
        for (int j = 0; j < HID; ++j) acc[j] += __shfl_xor(acc[j], off, 64);
    }
    if (sub == 0 && node < N) {
        float din = (float)(s1 - s0);
        float nin = rsqrtf(fmaxf(din, 1.f));
        float nout = rsqrtf(fmaxf(deg_out[node], 1.f));
        float dot = 0.f;
        #pragma unroll
        for (int j = 0; j < HID; ++j) {
            float y = fmaxf(acc[j] * nin + b1[j], 0.f);
            dot += y * W2[j];
        }
        h2[node] = dot * nout;
    }
}

// ---------------- agg2G4: 4 lanes per node over h2, fused final output ----------------
__global__ __launch_bounds__(256) void agg2G4_kernel(const unsigned int* __restrict__ bucketG,
        const int* __restrict__ row_ptr, const float* __restrict__ h2,
        const float* __restrict__ b2, float* __restrict__ out, int N) {
    int tid = blockIdx.x * 256 + threadIdx.x;
    int node = tid >> 2, sub = tid & 3;
    int s0 = row_ptr[node], s1 = row_ptr[node + 1];
    float a = 0.f;
    for (int e = s0 + sub; e < s1; e += 4) a += h2[bucketG[e]];
    a += __shfl_xor(a, 1, 64);
    a += __shfl_xor(a, 2, 64);
    if (sub == 0 && node < N) {
        float nin = rsqrtf(fmaxf((float)(s1 - s0), 1.f));
        out[node] = a * nin + b2[0];
    }
}

extern "C" void kernel_launch(void* const* d_in, const int* in_sizes, int n_in,
                              void* d_out, int out_size, void* d_ws, size_t ws_size,
                              hipStream_t stream) {
    const float* x  = (const float*)d_in[0];
    const int* src  = (const int*)d_in[1];
    const int* dst  = (const int*)d_in[2];
    const float* W1 = (const float*)d_in[3];
    const float* b1 = (const float*)d_in[4];
    const float* W2 = (const float*)d_in[5];
    const float* b2 = (const float*)d_in[6];
    float* out = (float*)d_out;

    const int N  = out_size;     // 100000
    const int E  = in_sizes[1];  // 3200000
    const int RT = (N + TW - 1) / TW;                    // 391 tiles
    const int chunk = (((E + CCH - 1) / CCH) + 3) & ~3;  // mult of 4 (int4)

    // workspace layout (every region fully written before read each call; no memset)
    float* ws      = (float*)d_ws;
    float* deg_out = ws;                        // N
    float* h2      = deg_out + N;               // N
    int*   cntS    = (int*)(h2 + N);            // CCH*RT
    int*   cntD    = cntS + (size_t)CCH * RT;   // CCH*RT
    int*   totS    = cntD + (size_t)CCH * RT;   // RT
    int*   baseS   = totS + RT;                 // RT+1
    int*   totD    = baseS + RT + 1;            // RT
    int*   baseD   = totD + RT;                 // RT+1
    int*   row_ptr = baseD + RT + 1;            // RT*TW+1
    unsigned int* bucketT = (unsigned int*)(row_ptr + (size_t)RT * TW + 1);  // E
    unsigned int* bucketG = bucketT + E;        // E
    uint4* h4 = (uint4*)(((uintptr_t)(bucketG + E) + 15) & ~(uintptr_t)15);  // N
    unsigned char* bucket_s = (unsigned char*)(h4 + N);  // E bytes

    pass1AB_kernel<<<CCH, 1024, 0, stream>>>(src, dst, cntS, cntD, E, RT, chunk);
    scan1_kernel<<<dim3(RT, 2), 256, 0, stream>>>(cntS, cntD, totS, totD, RT);
    scan2_kernel<<<2, 256, 0, stream>>>(totS, totD, baseS, baseD, RT);
    scatterAB_kernel<<<CCH, 1024, 0, stream>>>(src, dst, cntS, cntD, baseS, baseD,
                                               bucket_s, bucketT, E, RT, chunk);
    degout_kernel<<<RT, 256, 0, stream>>>(bucket_s, baseS, deg_out, N);
    passC_kernel<<<RT, 512, 0, stream>>>(bucketT, baseD, bucketG, row_ptr, E, RT);
    conv1_kernel<<<(N + 31) / 32, 256, 0, stream>>>(x, W1, deg_out, h4, N);
    agg1G4_kernel<<<RT * 4, 256, 0, stream>>>(bucketG, row_ptr, h4, deg_out, b1, W2, h2, N);
    agg2G4_kernel<<<RT * 4, 256, 0, stream>>>(bucketG, row_ptr, h2, b2, out, N);
}

// Round 9
// 130.011 us; speedup vs baseline: 2.7917x; 1.0401x over previous
//
#include <hip/hip_runtime.h>
#include <hip/hip_bf16.h>
#include <hip/hip_fp16.h>

#define IN_DIM 128
#define HID 8
#define TW 256       // node tile width (sort + CSR granularity)
#define MAXT 512     // max tiles (N<=131072)
#define CCH 256      // edge chunks (one 1024-thread block each; 256 = 8 XCDs * 32)

// ---------------- pass1AB: per-chunk src-tile AND dst-tile histograms ----------------
__global__ __launch_bounds__(1024) void pass1AB_kernel(const int* __restrict__ src, const int* __restrict__ dst,
        int* __restrict__ cntS, int* __restrict__ cntD, int E, int RT, int chunk) {
    __shared__ int cs[MAXT], cd[MAXT];
    int t = threadIdx.x, c = blockIdx.x;
    for (int i = t; i < RT; i += 1024) { cs[i] = 0; cd[i] = 0; }
    __syncthreads();
    int lo = c * chunk, hi = min(lo + chunk, E);
    if (lo < hi) {
        const int4* s4 = reinterpret_cast<const int4*>(src);
        const int4* d4 = reinterpret_cast<const int4*>(dst);
        int q0 = lo >> 2, q1 = hi >> 2;
        for (int q = q0 + t; q < q1; q += 1024) {
            int4 s = s4[q], d = d4[q];
            atomicAdd(&cs[s.x >> 8], 1); atomicAdd(&cs[s.y >> 8], 1);
            atomicAdd(&cs[s.z >> 8], 1); atomicAdd(&cs[s.w >> 8], 1);
            atomicAdd(&cd[d.x >> 8], 1); atomicAdd(&cd[d.y >> 8], 1);
            atomicAdd(&cd[d.z >> 8], 1); atomicAdd(&cd[d.w >> 8], 1);
        }
        for (int i = (q1 << 2) + t; i < hi; i += 1024) {
            atomicAdd(&cs[src[i] >> 8], 1);
            atomicAdd(&cd[dst[i] >> 8], 1);
        }
    }
    __syncthreads();
    for (int i = t; i < RT; i += 1024) {
        cntS[(size_t)c * RT + i] = cs[i];
        cntD[(size_t)c * RT + i] = cd[i];
    }
}

// ---------------- scan1: per-tile exclusive scan over 256 chunks (S and D via blockIdx.y) ----------------
__global__ __launch_bounds__(256) void scan1_kernel(int* __restrict__ cntS, int* __restrict__ cntD,
        int* __restrict__ totS, int* __restrict__ totD, int RT) {
    int r = blockIdx.x;
    int* cnt = blockIdx.y ? cntD : cntS;
    int* tot = blockIdx.y ? totD : totS;
    __shared__ int sh[256];
    int t = threadIdx.x;
    int e = cnt[(size_t)t * RT + r];
    sh[t] = e;
    __syncthreads();
    for (int off = 1; off < 256; off <<= 1) {
        int v = (t >= off) ? sh[t - off] : 0;
        __syncthreads();
        sh[t] += v;
        __syncthreads();
    }
    cnt[(size_t)t * RT + r] = sh[t] - e;
    if (t == 255) tot[r] = sh[255];
}

// ---------------- scan2: exclusive scan of tile totals -> bases (S and D via blockIdx.x) ----------------
__global__ __launch_bounds__(256) void scan2_kernel(const int* __restrict__ totS, const int* __restrict__ totD,
        int* __restrict__ baseS, int* __restrict__ baseD, int RT) {
    const int* tot = blockIdx.x ? totD : totS;
    int* base = blockIdx.x ? baseD : baseS;
    __shared__ int sh[256];
    int t = threadIdx.x;
    int K = (RT + 255) / 256;   // <=2
    int vals[4];
    int s = 0;
    for (int k = 0; k < K; ++k) {
        int i = t * K + k;
        int v = (i < RT) ? tot[i] : 0;
        vals[k] = v; s += v;
    }
    sh[t] = s;
    __syncthreads();
    for (int off = 1; off < 256; off <<= 1) {
        int v = (t >= off) ? sh[t - off] : 0;
        __syncthreads();
        sh[t] += v;
        __syncthreads();
    }
    int exc = sh[t] - s;
    for (int k = 0; k < K; ++k) {
        int i = t * K + k;
        if (i < RT) base[i] = exc;
        exc += vals[k];
    }
    if (t == 255) base[RT] = sh[255];
}

// ---------------- scatterAB: src-tile byte locals + dst-tile packed records ----------------
// XCD-affinity swizzle: memory-adjacent chunks map to the same XCD so run-boundary
// cache lines are shared within one L2 instead of ping-ponging across XCDs.
__global__ __launch_bounds__(1024) void scatterAB_kernel(const int* __restrict__ src, const int* __restrict__ dst,
        const int* __restrict__ cntS, const int* __restrict__ cntD,
        const int* __restrict__ baseS, const int* __restrict__ baseD,
        unsigned char* __restrict__ bucket_s, unsigned int* __restrict__ bucketT,
        int E, int RT, int chunk) {
    __shared__ int os[MAXT], od[MAXT];
    int t = threadIdx.x;
    int c = ((blockIdx.x & 7) << 5) | (blockIdx.x >> 3);   // bid -> chunk, same-XCD adjacency
    for (int i = t; i < RT; i += 1024) {
        os[i] = baseS[i] + cntS[(size_t)c * RT + i];
        od[i] = baseD[i] + cntD[(size_t)c * RT + i];
    }
    __syncthreads();
    int lo = c * chunk, hi = min(lo + chunk, E);
    if (lo >= hi) return;
    const int4* s4 = reinterpret_cast<const int4*>(src);
    const int4* d4 = reinterpret_cast<const int4*>(dst);
    int q0 = lo >> 2, q1 = hi >> 2;
    for (int q = q0 + t; q < q1; q += 1024) {
        int4 s = s4[q], d = d4[q];
        int p;
        p = atomicAdd(&os[s.x >> 8], 1); bucket_s[p] = (unsigned char)(s.x & 255);
        p = atomicAdd(&os[s.y >> 8], 1); bucket_s[p] = (unsigned char)(s.y & 255);
        p = atomicAdd(&os[s.z >> 8], 1); bucket_s[p] = (unsigned char)(s.z & 255);
        p = atomicAdd(&os[s.w >> 8], 1); bucket_s[p] = (unsigned char)(s.w & 255);
        p = atomicAdd(&od[d.x >> 8], 1); bucketT[p] = ((unsigned)s.x << 8) | (unsigned)(d.x & 255);
        p = atomicAdd(&od[d.y >> 8], 1); bucketT[p] = ((unsigned)s.y << 8) | (unsigned)(d.y & 255);
        p = atomicAdd(&od[d.z >> 8], 1); bucketT[p] = ((unsigned)s.z << 8) | (unsigned)(d.z & 255);
        p = atomicAdd(&od[d.w >> 8], 1); bucketT[p] = ((unsigned)s.w << 8) | (unsigned)(d.w & 255);
    }
    for (int i = (q1 << 2) + t; i < hi; i += 1024) {
        int s = src[i], d = dst[i];
        int p = atomicAdd(&os[s >> 8], 1);
        bucket_s[p] = (unsigned char)(s & 255);
        p = atomicAdd(&od[d >> 8], 1);
        bucketT[p] = ((unsigned)s << 8) | (unsigned)(d & 255);
    }
}

// ---------------- passC: full sort within dst-tile -> bucketG (src ids) + CSR row_ptr ----------------
__global__ __launch_bounds__(512) void passC_kernel(const unsigned int* __restrict__ bucketT,
        const int* __restrict__ baseD, unsigned int* __restrict__ bucketG,
        int* __restrict__ row_ptr, int E, int RT) {
    __shared__ int cnt[TW];
    __shared__ int scn[TW];
    __shared__ int start[TW];
    int r = blockIdx.x, t = threadIdx.x;
    if (t < TW) cnt[t] = 0;
    __syncthreads();
    int lo = baseD[r], hi = baseD[r + 1];
    for (int i = lo + t; i < hi; i += 512) atomicAdd(&cnt[bucketT[i] & 255u], 1);
    __syncthreads();
    if (t < TW) scn[t] = cnt[t];
    __syncthreads();
    for (int off = 1; off < TW; off <<= 1) {
        int v = 0;
        if (t < TW && t >= off) v = scn[t - off];
        __syncthreads();
        if (t < TW) scn[t] += v;
        __syncthreads();
    }
    if (t < TW) {
        int ex = scn[t] - cnt[t];
        start[t] = ex;
        row_ptr[r * TW + t] = lo + ex;
    }
    if (r == 0 && t == 0) row_ptr[RT * TW] = E;
    __syncthreads();
    for (int i = lo + t; i < hi; i += 512) {
        unsigned v = bucketT[i];
        int p = atomicAdd(&start[v & 255u], 1);
        bucketG[lo + p] = v >> 8;
    }
}

// ---------------- conv1deg: fused per-src-tile degout + conv1 -> deg_out, h4 ----------------
__global__ __launch_bounds__(256) void conv1deg_kernel(
        const unsigned char* __restrict__ bucket_s, const int* __restrict__ baseS,
        const float* __restrict__ x, const float* __restrict__ W1,
        float* __restrict__ deg_out, uint4* __restrict__ h4, int N) {
    __shared__ float wt[HID * 132];
    __shared__ int cnt[TW];
    __shared__ float nrmS[TW];
    int r = blockIdx.x, t = threadIdx.x;
    for (int i = t; i < IN_DIM * HID; i += 256) {
        int k = i >> 3, j = i & 7;
        wt[j * 132 + k] = W1[i];
    }
    cnt[t] = 0;
    __syncthreads();
    // degree histogram of this src tile (word reads of byte locals)
    int lo = baseS[r], hi = baseS[r + 1];
    int a0 = min((lo + 3) & ~3, hi), a1 = max(hi & ~3, a0);
    for (int i = lo + t; i < a0; i += 256) atomicAdd(&cnt[bucket_s[i]], 1);
    const unsigned* w4 = reinterpret_cast<const unsigned*>(bucket_s);
    for (int q = (a0 >> 2) + t; q < (a1 >> 2); q += 256) {
        unsigned w = w4[q];
        atomicAdd(&cnt[w & 255], 1);
        atomicAdd(&cnt[(w >> 8) & 255], 1);
        atomicAdd(&cnt[(w >> 16) & 255], 1);
        atomicAdd(&cnt[w >> 24], 1);
    }
    for (int i = a1 + t; i < hi; i += 256) atomicAdd(&cnt[bucket_s[i]], 1);
    __syncthreads();
    {
        int node = r * TW + t;
        if (node < N) deg_out[node] = (float)cnt[t];
        nrmS[t] = rsqrtf(fmaxf((float)cnt[t], 1.0f));
    }
    __syncthreads();
    // conv: 8 lanes per node, 32 nodes per sweep, 8 sweeps
    int grp = t >> 3, lane = t & 7;
    #pragma unroll
    for (int sweep = 0; sweep < 8; ++sweep) {
        int nl = sweep * 32 + grp;
        int node = r * TW + nl;
        if (node < N) {
            const float4* xp = reinterpret_cast<const float4*>(x + (size_t)node * IN_DIM);
            float4 xv[4];
            #pragma unroll
            for (int m = 0; m < 4; ++m) xv[m] = xp[lane + m * 8];
            float acc[HID];
            #pragma unroll
            for (int j = 0; j < HID; ++j) acc[j] = 0.f;
            #pragma unroll
            for (int j = 0; j < HID; ++j) {
                #pragma unroll
                for (int m = 0; m < 4; ++m) {
                    float4 wv = *reinterpret_cast<const float4*>(&wt[j * 132 + lane * 4 + m * 32]);
                    acc[j] += xv[m].x * wv.x + xv[m].y * wv.y + xv[m].z * wv.z + xv[m].w * wv.w;
                }
            }
            #pragma unroll
            for (int off = 1; off < 8; off <<= 1) {
                #pragma unroll
                for (int j = 0; j < HID; ++j) acc[j] += __shfl_xor(acc[j], off, 64);
            }
            if (lane == 0) {
                float nrm = nrmS[nl];
                __half2 p0 = __floats2half2_rn(acc[0] * nrm, acc[1] * nrm);
                __half2 p1 = __floats2half2_rn(acc[2] * nrm, acc[3] * nrm);
                __half2 p2 = __floats2half2_rn(acc[4] * nrm, acc[5] * nrm);
                __half2 p3 = __floats2half2_rn(acc[6] * nrm, acc[7] * nrm);
                uint4 o;
                o.x = *reinterpret_cast<unsigned*>(&p0);
                o.y = *reinterpret_cast<unsigned*>(&p1);
                o.z = *reinterpret_cast<unsigned*>(&p2);
                o.w = *reinterpret_cast<unsigned*>(&p3);
                h4[node] = o;
            }
        }
    }
}

// ---------------- agg1G4: 4 lanes per node, register accumulation, fused finalize -> h2 ----------------
__device__ __forceinline__ void accAdd(float* acc, uint4 g) {
    __half2 q0 = *reinterpret_cast<__half2*>(&g.x);
    __half2 q1 = *reinterpret_cast<__half2*>(&g.y);
    __half2 q2 = *reinterpret_cast<__half2*>(&g.z);
    __half2 q3 = *reinterpret_cast<__half2*>(&g.w);
    float2 f0 = __half22float2(q0), f1 = __half22float2(q1);
    float2 f2 = __half22float2(q2), f3 = __half22float2(q3);
    acc[0] += f0.x; acc[1] += f0.y;
    acc[2] += f1.x; acc[3] += f1.y;
    acc[4] += f2.x; acc[5] += f2.y;
    acc[6] += f3.x; acc[7] += f3.y;
}

__global__ __launch_bounds__(256) void agg1G4_kernel(const unsigned int* __restrict__ bucketG,
        const int* __restrict__ row_ptr, const uint4* __restrict__ h4,
        const float* __restrict__ deg_out, const float* __restrict__ b1, const float* __restrict__ W2,
        float* __restrict__ h2, int N) {
    int tid = blockIdx.x * 256 + threadIdx.x;
    int node = tid >> 2, sub = tid & 3;
    int s0 = row_ptr[node], s1 = row_ptr[node + 1];
    float acc[HID];
    #pragma unroll
    for (int j = 0; j < HID; ++j) acc[j] = 0.f;
    for (int e = s0 + sub; e < s1; e += 4) accAdd(acc, h4[bucketG[e]]);
    #pragma unroll
    for (int off = 1; off < 4; off <<= 1) {
        #pragma unroll
        for (int j = 0; j < HID; ++j) acc[j] += __shfl_xor(acc[j], off, 64);
    }
    if (sub == 0 && node < N) {
        float din = (float)(s1 - s0);
        float nin = rsqrtf(fmaxf(din, 1.f));
        float nout = rsqrtf(fmaxf(deg_out[node], 1.f));
        float dot = 0.f;
        #pragma unroll
        for (int j = 0; j < HID; ++j) {
            float y = fmaxf(acc[j] * nin + b1[j], 0.f);
            dot += y * W2[j];
        }
        h2[node] = dot * nout;
    }
}

// ---------------- agg2G4: 4 lanes per node over h2, fused final output ----------------
__global__ __launch_bounds__(256) void agg2G4_kernel(const unsigned int* __restrict__ bucketG,
        const int* __restrict__ row_ptr, const float* __restrict__ h2,
        const float* __restrict__ b2, float* __restrict__ out, int N) {
    int tid = blockIdx.x * 256 + threadIdx.x;
    int node = tid >> 2, sub = tid & 3;
    int s0 = row_ptr[node], s1 = row_ptr[node + 1];
    float a = 0.f;
    for (int e = s0 + sub; e < s1; e += 4) a += h2[bucketG[e]];
    a += __shfl_xor(a, 1, 64);
    a += __shfl_xor(a, 2, 64);
    if (sub == 0 && node < N) {
        float nin = rsqrtf(fmaxf((float)(s1 - s0), 1.f));
        out[node] = a * nin + b2[0];
    }
}

extern "C" void kernel_launch(void* const* d_in, const int* in_sizes, int n_in,
                              void* d_out, int out_size, void* d_ws, size_t ws_size,
                              hipStream_t stream) {
    const float* x  = (const float*)d_in[0];
    const int* src  = (const int*)d_in[1];
    const int* dst  = (const int*)d_in[2];
    const float* W1 = (const float*)d_in[3];
    const float* b1 = (const float*)d_in[4];
    const float* W2 = (const float*)d_in[5];
    const float* b2 = (const float*)d_in[6];
    float* out = (float*)d_out;

    const int N  = out_size;     // 100000
    const int E  = in_sizes[1];  // 3200000
    const int RT = (N + TW - 1) / TW;                    // 391 tiles
    const int chunk = (((E + CCH - 1) / CCH) + 3) & ~3;  // mult of 4 (int4)

    // workspace layout (every region fully written before read each call; no memset)
    float* ws      = (float*)d_ws;
    float* deg_out = ws;                        // N
    float* h2      = deg_out + N;               // N
    int*   cntS    = (int*)(h2 + N);            // CCH*RT
    int*   cntD    = cntS + (size_t)CCH * RT;   // CCH*RT
    int*   totS    = cntD + (size_t)CCH * RT;   // RT
    int*   baseS   = totS + RT;                 // RT+1
    int*   totD    = baseS + RT + 1;            // RT
    int*   baseD   = totD + RT;                 // RT+1
    int*   row_ptr = baseD + RT + 1;            // RT*TW+1
    unsigned int* bucketT = (unsigned int*)(row_ptr + (size_t)RT * TW + 1);  // E
    unsigned int* bucketG = bucketT + E;        // E
    uint4* h4 = (uint4*)(((uintptr_t)(bucketG + E) + 15) & ~(uintptr_t)15);  // N
    unsigned char* bucket_s = (unsigned char*)(h4 + N);  // E bytes

    pass1AB_kernel<<<CCH, 1024, 0, stream>>>(src, dst, cntS, cntD, E, RT, chunk);
    scan1_kernel<<<dim3(RT, 2), 256, 0, stream>>>(cntS, cntD, totS, totD, RT);
    scan2_kernel<<<2, 256, 0, stream>>>(totS, totD, baseS, baseD, RT);
    scatterAB_kernel<<<CCH, 1024, 0, stream>>>(src, dst, cntS, cntD, baseS, baseD,
                                               bucket_s, bucketT, E, RT, chunk);
    passC_kernel<<<RT, 512, 0, stream>>>(bucketT, baseD, bucketG, row_ptr, E, RT);
    conv1deg_kernel<<<RT, 256, 0, stream>>>(bucket_s, baseS, x, W1, deg_out, h4, N);
    agg1G4_kernel<<<RT * 4, 256, 0, stream>>>(bucketG, row_ptr, h4, deg_out, b1, W2, h2, N);
    agg2G4_kernel<<<RT * 4, 256, 0, stream>>>(bucketG, row_ptr, h2, b2, out, N);
}

// Round 10
// 113.907 us; speedup vs baseline: 3.1864x; 1.1414x over previous
//
#include <hip/hip_runtime.h>
#include <hip/hip_bf16.h>
#include <hip/hip_fp16.h>

#define IN_DIM 128
#define HID 8
#define TW 256       // node tile width (sort + CSR granularity)
#define MAXT 512     // max tiles (N<=131072)
#define CCH 256      // edge chunks (one 1024-thread block each; 256 = 8 XCDs * 32)
#define CAP 12288    // LDS sorted-run capacity (uints); tile runs ~8200 for this input

// ---------------- pass1AB: per-chunk src-tile AND dst-tile histograms ----------------
__global__ __launch_bounds__(1024) void pass1AB_kernel(const int* __restrict__ src, const int* __restrict__ dst,
        int* __restrict__ cntS, int* __restrict__ cntD, int E, int RT, int chunk) {
    __shared__ int cs[MAXT], cd[MAXT];
    int t = threadIdx.x, c = blockIdx.x;
    for (int i = t; i < RT; i += 1024) { cs[i] = 0; cd[i] = 0; }
    __syncthreads();
    int lo = c * chunk, hi = min(lo + chunk, E);
    if (lo < hi) {
        const int4* s4 = reinterpret_cast<const int4*>(src);
        const int4* d4 = reinterpret_cast<const int4*>(dst);
        int q0 = lo >> 2, q1 = hi >> 2;
        for (int q = q0 + t; q < q1; q += 1024) {
            int4 s = s4[q], d = d4[q];
            atomicAdd(&cs[s.x >> 8], 1); atomicAdd(&cs[s.y >> 8], 1);
            atomicAdd(&cs[s.z >> 8], 1); atomicAdd(&cs[s.w >> 8], 1);
            atomicAdd(&cd[d.x >> 8], 1); atomicAdd(&cd[d.y >> 8], 1);
            atomicAdd(&cd[d.z >> 8], 1); atomicAdd(&cd[d.w >> 8], 1);
        }
        for (int i = (q1 << 2) + t; i < hi; i += 1024) {
            atomicAdd(&cs[src[i] >> 8], 1);
            atomicAdd(&cd[dst[i] >> 8], 1);
        }
    }
    __syncthreads();
    for (int i = t; i < RT; i += 1024) {
        cntS[(size_t)c * RT + i] = cs[i];
        cntD[(size_t)c * RT + i] = cd[i];
    }
}

// ---------------- scan1: per-tile exclusive scan over 256 chunks (S and D via blockIdx.y) ----------------
__global__ __launch_bounds__(256) void scan1_kernel(int* __restrict__ cntS, int* __restrict__ cntD,
        int* __restrict__ totS, int* __restrict__ totD, int RT) {
    int r = blockIdx.x;
    int* cnt = blockIdx.y ? cntD : cntS;
    int* tot = blockIdx.y ? totD : totS;
    __shared__ int sh[256];
    int t = threadIdx.x;
    int e = cnt[(size_t)t * RT + r];
    sh[t] = e;
    __syncthreads();
    for (int off = 1; off < 256; off <<= 1) {
        int v = (t >= off) ? sh[t - off] : 0;
        __syncthreads();
        sh[t] += v;
        __syncthreads();
    }
    cnt[(size_t)t * RT + r] = sh[t] - e;
    if (t == 255) tot[r] = sh[255];
}

// ---------------- scan2: exclusive scan of tile totals -> bases (S and D via blockIdx.x) ----------------
__global__ __launch_bounds__(256) void scan2_kernel(const int* __restrict__ totS, const int* __restrict__ totD,
        int* __restrict__ baseS, int* __restrict__ baseD, int RT) {
    const int* tot = blockIdx.x ? totD : totS;
    int* base = blockIdx.x ? baseD : baseS;
    __shared__ int sh[256];
    int t = threadIdx.x;
    int K = (RT + 255) / 256;   // <=2
    int vals[4];
    int s = 0;
    for (int k = 0; k < K; ++k) {
        int i = t * K + k;
        int v = (i < RT) ? tot[i] : 0;
        vals[k] = v; s += v;
    }
    sh[t] = s;
    __syncthreads();
    for (int off = 1; off < 256; off <<= 1) {
        int v = (t >= off) ? sh[t - off] : 0;
        __syncthreads();
        sh[t] += v;
        __syncthreads();
    }
    int exc = sh[t] - s;
    for (int k = 0; k < K; ++k) {
        int i = t * K + k;
        if (i < RT) base[i] = exc;
        exc += vals[k];
    }
    if (t == 255) base[RT] = sh[255];
}

// ---------------- scatterAB: src-tile byte locals + dst-tile packed records ----------------
// XCD-affinity swizzle keeps memory-adjacent chunks on one XCD (run-boundary lines stay local).
__global__ __launch_bounds__(1024) void scatterAB_kernel(const int* __restrict__ src, const int* __restrict__ dst,
        const int* __restrict__ cntS, const int* __restrict__ cntD,
        const int* __restrict__ baseS, const int* __restrict__ baseD,
        unsigned char* __restrict__ bucket_s, unsigned int* __restrict__ bucketT,
        int E, int RT, int chunk) {
    __shared__ int os[MAXT], od[MAXT];
    int t = threadIdx.x;
    int c = ((blockIdx.x & 7) << 5) | (blockIdx.x >> 3);   // bid -> chunk, same-XCD adjacency
    for (int i = t; i < RT; i += 1024) {
        os[i] = baseS[i] + cntS[(size_t)c * RT + i];
        od[i] = baseD[i] + cntD[(size_t)c * RT + i];
    }
    __syncthreads();
    int lo = c * chunk, hi = min(lo + chunk, E);
    if (lo >= hi) return;
    const int4* s4 = reinterpret_cast<const int4*>(src);
    const int4* d4 = reinterpret_cast<const int4*>(dst);
    int q0 = lo >> 2, q1 = hi >> 2;
    for (int q = q0 + t; q < q1; q += 1024) {
        int4 s = s4[q], d = d4[q];
        int p;
        p = atomicAdd(&os[s.x >> 8], 1); bucket_s[p] = (unsigned char)(s.x & 255);
        p = atomicAdd(&os[s.y >> 8], 1); bucket_s[p] = (unsigned char)(s.y & 255);
        p = atomicAdd(&os[s.z >> 8], 1); bucket_s[p] = (unsigned char)(s.z & 255);
        p = atomicAdd(&os[s.w >> 8], 1); bucket_s[p] = (unsigned char)(s.w & 255);
        p = atomicAdd(&od[d.x >> 8], 1); bucketT[p] = ((unsigned)s.x << 8) | (unsigned)(d.x & 255);
        p = atomicAdd(&od[d.y >> 8], 1); bucketT[p] = ((unsigned)s.y << 8) | (unsigned)(d.y & 255);
        p = atomicAdd(&od[d.z >> 8], 1); bucketT[p] = ((unsigned)s.z << 8) | (unsigned)(d.z & 255);
        p = atomicAdd(&od[d.w >> 8], 1); bucketT[p] = ((unsigned)s.w << 8) | (unsigned)(d.w & 255);
    }
    for (int i = (q1 << 2) + t; i < hi; i += 1024) {
        int s = src[i], d = dst[i];
        int p = atomicAdd(&os[s >> 8], 1);
        bucket_s[p] = (unsigned char)(s & 255);
        p = atomicAdd(&od[d >> 8], 1);
        bucketT[p] = ((unsigned)s << 8) | (unsigned)(d & 255);
    }
}

// ---------------- conv1deg: fused per-src-tile degout + conv1 -> deg_out, h4 ----------------
__global__ __launch_bounds__(256) void conv1deg_kernel(
        const unsigned char* __restrict__ bucket_s, const int* __restrict__ baseS,
        const float* __restrict__ x, const float* __restrict__ W1,
        float* __restrict__ deg_out, uint4* __restrict__ h4, int N) {
    __shared__ float wt[HID * 132];
    __shared__ int cnt[TW];
    __shared__ float nrmS[TW];
    int r = blockIdx.x, t = threadIdx.x;
    for (int i = t; i < IN_DIM * HID; i += 256) {
        int k = i >> 3, j = i & 7;
        wt[j * 132 + k] = W1[i];
    }
    cnt[t] = 0;
    __syncthreads();
    int lo = baseS[r], hi = baseS[r + 1];
    int a0 = min((lo + 3) & ~3, hi), a1 = max(hi & ~3, a0);
    for (int i = lo + t; i < a0; i += 256) atomicAdd(&cnt[bucket_s[i]], 1);
    const unsigned* w4 = reinterpret_cast<const unsigned*>(bucket_s);
    for (int q = (a0 >> 2) + t; q < (a1 >> 2); q += 256) {
        unsigned w = w4[q];
        atomicAdd(&cnt[w & 255], 1);
        atomicAdd(&cnt[(w >> 8) & 255], 1);
        atomicAdd(&cnt[(w >> 16) & 255], 1);
        atomicAdd(&cnt[w >> 24], 1);
    }
    for (int i = a1 + t; i < hi; i += 256) atomicAdd(&cnt[bucket_s[i]], 1);
    __syncthreads();
    {
        int node = r * TW + t;
        if (node < N) deg_out[node] = (float)cnt[t];
        nrmS[t] = rsqrtf(fmaxf((float)cnt[t], 1.0f));
    }
    __syncthreads();
    int grp = t >> 3, lane = t & 7;
    #pragma unroll
    for (int sweep = 0; sweep < 8; ++sweep) {
        int nl = sweep * 32 + grp;
        int node = r * TW + nl;
        if (node < N) {
            const float4* xp = reinterpret_cast<const float4*>(x + (size_t)node * IN_DIM);
            float4 xv[4];
            #pragma unroll
            for (int m = 0; m < 4; ++m) xv[m] = xp[lane + m * 8];
            float acc[HID];
            #pragma unroll
            for (int j = 0; j < HID; ++j) acc[j] = 0.f;
            #pragma unroll
            for (int j = 0; j < HID; ++j) {
                #pragma unroll
                for (int m = 0; m < 4; ++m) {
                    float4 wv = *reinterpret_cast<const float4*>(&wt[j * 132 + lane * 4 + m * 32]);
                    acc[j] += xv[m].x * wv.x + xv[m].y * wv.y + xv[m].z * wv.z + xv[m].w * wv.w;
                }
            }
            #pragma unroll
            for (int off = 1; off < 8; off <<= 1) {
                #pragma unroll
                for (int j = 0; j < HID; ++j) acc[j] += __shfl_xor(acc[j], off, 64);
            }
            if (lane == 0) {
                float nrm = nrmS[nl];
                __half2 p0 = __floats2half2_rn(acc[0] * nrm, acc[1] * nrm);
                __half2 p1 = __floats2half2_rn(acc[2] * nrm, acc[3] * nrm);
                __half2 p2 = __floats2half2_rn(acc[4] * nrm, acc[5] * nrm);
                __half2 p3 = __floats2half2_rn(acc[6] * nrm, acc[7] * nrm);
                uint4 o;
                o.x = *reinterpret_cast<unsigned*>(&p0);
                o.y = *reinterpret_cast<unsigned*>(&p1);
                o.z = *reinterpret_cast<unsigned*>(&p2);
                o.w = *reinterpret_cast<unsigned*>(&p3);
                h4[node] = o;
            }
        }
    }
}

// ---------------- sortagg1: fused within-tile sort + layer-1 aggregation ----------------
__device__ __forceinline__ void accAdd(float* acc, uint4 g) {
    __half2 q0 = *reinterpret_cast<__half2*>(&g.x);
    __half2 q1 = *reinterpret_cast<__half2*>(&g.y);
    __half2 q2 = *reinterpret_cast<__half2*>(&g.z);
    __half2 q3 = *reinterpret_cast<__half2*>(&g.w);
    float2 f0 = __half22float2(q0), f1 = __half22float2(q1);
    float2 f2 = __half22float2(q2), f3 = __half22float2(q3);
    acc[0] += f0.x; acc[1] += f0.y;
    acc[2] += f1.x; acc[3] += f1.y;
    acc[4] += f2.x; acc[5] += f2.y;
    acc[6] += f3.x; acc[7] += f3.y;
}

__global__ __launch_bounds__(512) void sortagg1_kernel(
        const unsigned int* __restrict__ bucketT, const int* __restrict__ baseD,
        unsigned int* __restrict__ bucketG, int* __restrict__ row_ptr,
        const uint4* __restrict__ h4, const float* __restrict__ deg_out,
        const float* __restrict__ b1, const float* __restrict__ W2,
        float* __restrict__ h2, int E, int RT, int N) {
    __shared__ unsigned sorted[CAP];
    __shared__ int cnt[TW], scn[TW], start[TW];
    __shared__ float b1s[HID], w2s[HID];
    int r = blockIdx.x, t = threadIdx.x;
    if (t < TW) cnt[t] = 0;
    if (t < HID) { b1s[t] = b1[t]; w2s[t] = W2[t]; }
    __syncthreads();
    int lo = baseD[r], hi = baseD[r + 1], len = hi - lo;
    // phase 1: histogram of dst locals (sequential global read)
    for (int i = lo + t; i < hi; i += 512) atomicAdd(&cnt[bucketT[i] & 255u], 1);
    __syncthreads();
    // phase 2: scan
    if (t < TW) scn[t] = cnt[t];
    __syncthreads();
    for (int off = 1; off < TW; off <<= 1) {
        int v = 0;
        if (t < TW && t >= off) v = scn[t - off];
        __syncthreads();
        if (t < TW) scn[t] += v;
        __syncthreads();
    }
    if (t < TW) {
        start[t] = scn[t] - cnt[t];
        row_ptr[r * TW + t] = lo + scn[t] - cnt[t];
    }
    if (r == 0 && t == 0) row_ptr[RT * TW] = E;
    __syncthreads();
    bool fits = (len <= CAP);
    // phase 3: scatter to sorted order (LDS if it fits, else global)
    if (fits) {
        for (int i = lo + t; i < hi; i += 512) {
            unsigned v = bucketT[i];
            int p = atomicAdd(&start[v & 255u], 1);
            sorted[p] = v >> 8;
        }
        __syncthreads();
        // phase 4: sequential coalesced bucketG write (for agg2)
        for (int i = t; i < len; i += 512) bucketG[lo + i] = sorted[i];
    } else {
        for (int i = lo + t; i < hi; i += 512) {
            unsigned v = bucketT[i];
            int p = atomicAdd(&start[v & 255u], 1);
            bucketG[lo + p] = v >> 8;
        }
        __syncthreads();
    }
    // phase 5: aggregation, 4 lanes per node, 2 halves (512 threads / 256 nodes)
    #pragma unroll
    for (int half = 0; half < 2; ++half) {
        int nl = (t >> 2) + half * 128;
        int sub = t & 3;
        int node = r * TW + nl;
        int end = scn[nl], beg = end - cnt[nl];
        float acc[HID];
        #pragma unroll
        for (int j = 0; j < HID; ++j) acc[j] = 0.f;
        if (fits) {
            for (int e = beg + sub; e < end; e += 4) accAdd(acc, h4[sorted[e]]);
        } else {
            for (int e = beg + sub; e < end; e += 4) accAdd(acc, h4[bucketG[lo + e]]);
        }
        #pragma unroll
        for (int off = 1; off < 4; off <<= 1) {
            #pragma unroll
            for (int j = 0; j < HID; ++j) acc[j] += __shfl_xor(acc[j], off, 64);
        }
        if (sub == 0 && node < N) {
            float din = (float)(end - beg);
            float nin = rsqrtf(fmaxf(din, 1.f));
            float nout = rsqrtf(fmaxf(deg_out[node], 1.f));
            float dot = 0.f;
            #pragma unroll
            for (int j = 0; j < HID; ++j) {
                float y = fmaxf(acc[j] * nin + b1s[j], 0.f);
                dot += y * w2s[j];
            }
            h2[node] = dot * nout;
        }
    }
}

// ---------------- agg2G4: 4 lanes per node over h2, fused final output ----------------
__global__ __launch_bounds__(256) void agg2G4_kernel(const unsigned int* __restrict__ bucketG,
        const int* __restrict__ row_ptr, const float* __restrict__ h2,
        const float* __restrict__ b2, float* __restrict__ out, int N) {
    int tid = blockIdx.x * 256 + threadIdx.x;
    int node = tid >> 2, sub = tid & 3;
    int s0 = row_ptr[node], s1 = row_ptr[node + 1];
    float a = 0.f;
    for (int e = s0 + sub; e < s1; e += 4) a += h2[bucketG[e]];
    a += __shfl_xor(a, 1, 64);
    a += __shfl_xor(a, 2, 64);
    if (sub == 0 && node < N) {
        float nin = rsqrtf(fmaxf((float)(s1 - s0), 1.f));
        out[node] = a * nin + b2[0];
    }
}

extern "C" void kernel_launch(void* const* d_in, const int* in_sizes, int n_in,
                              void* d_out, int out_size, void* d_ws, size_t ws_size,
                              hipStream_t stream) {
    const float* x  = (const float*)d_in[0];
    const int* src  = (const int*)d_in[1];
    const int* dst  = (const int*)d_in[2];
    const float* W1 = (const float*)d_in[3];
    const float* b1 = (const float*)d_in[4];
    const float* W2 = (const float*)d_in[5];
    const float* b2 = (const float*)d_in[6];
    float* out = (float*)d_out;

    const int N  = out_size;     // 100000
    const int E  = in_sizes[1];  // 3200000
    const int RT = (N + TW - 1) / TW;                    // 391 tiles
    const int chunk = (((E + CCH - 1) / CCH) + 3) & ~3;  // mult of 4 (int4)

    // workspace layout (every region fully written before read each call; no memset)
    float* ws      = (float*)d_ws;
    float* deg_out = ws;                        // N
    float* h2      = deg_out + N;               // N
    int*   cntS    = (int*)(h2 + N);            // CCH*RT
    int*   cntD    = cntS + (size_t)CCH * RT;   // CCH*RT
    int*   totS    = cntD + (size_t)CCH * RT;   // RT
    int*   baseS   = totS + RT;                 // RT+1
    int*   totD    = baseS + RT + 1;            // RT
    int*   baseD   = totD + RT;                 // RT+1
    int*   row_ptr = baseD + RT + 1;            // RT*TW+1
    unsigned int* bucketT = (unsigned int*)(row_ptr + (size_t)RT * TW + 1);  // E
    unsigned int* bucketG = bucketT + E;        // E
    uint4* h4 = (uint4*)(((uintptr_t)(bucketG + E) + 15) & ~(uintptr_t)15);  // N
    unsigned char* bucket_s = (unsigned char*)(h4 + N);  // E bytes

    pass1AB_kernel<<<CCH, 1024, 0, stream>>>(src, dst, cntS, cntD, E, RT, chunk);
    scan1_kernel<<<dim3(RT, 2), 256, 0, stream>>>(cntS, cntD, totS, totD, RT);
    scan2_kernel<<<2, 256, 0, stream>>>(totS, totD, baseS, baseD, RT);
    scatterAB_kernel<<<CCH, 1024, 0, stream>>>(src, dst, cntS, cntD, baseS, baseD,
                                               bucket_s, bucketT, E, RT, chunk);
    conv1deg_kernel<<<RT, 256, 0, stream>>>(bucket_s, baseS, x, W1, deg_out, h4, N);
    sortagg1_kernel<<<RT, 512, 0, stream>>>(bucketT, baseD, bucketG, row_ptr,
                                            h4, deg_out, b1, W2, h2, E, RT, N);
    agg2G4_kernel<<<RT * 4, 256, 0, stream>>>(bucketG, row_ptr, h2, b2, out, N);
}